// Round 8
// baseline (414.854 us; speedup 1.0000x reference)
//
#include <hip/hip_runtime.h>
#include <hip/hip_bf16.h>

typedef unsigned short u16;
typedef unsigned int u32;
typedef __attribute__((ext_vector_type(8))) short short8;   // 8 bf16 MFMA frag
typedef __attribute__((ext_vector_type(4))) short short4v;  // 4 bf16
typedef __attribute__((ext_vector_type(4))) float floatx4;  // MFMA C/D frag

#define BB 8
#define LL 1024
#define DD 1024
#define HH 16
#define DHH 64
#define NEGBIG (-3.0e38f)
// q pre-scale folds log2e so softmax uses native v_exp_f32 (2^x): exact transform.
#define QSCALE 0.1803368801111204f   // 0.125 * log2(e)
#define LN2F   0.6931471805599453f   // top = S' * ln2 recovers raw scores
#define DEFER_THR 12.0f              // defer-max threshold (log2 domain): P <= 2^12

__device__ inline u16 f2b(float f) {
  union { __hip_bfloat16 h; u16 u; } cv;
  cv.h = __float2bfloat16(f);  // RNE
  return cv.u;
}
__device__ inline float b2f(u16 u) {
  union { u16 u; __hip_bfloat16 h; } cv;
  cv.u = u;
  return __bfloat162float(cv.h);
}
__device__ inline float fin(float v, float sentinel) {
  return (fabsf(v) < 1e30f) ? v : sentinel;
}
__device__ inline float fexp2(float x) {
#if __has_builtin(__builtin_amdgcn_exp2f)
  return __builtin_amdgcn_exp2f(x);
#else
  return exp2f(x);
#endif
}
// async global->LDS, 16B/lane; LDS dst = wave-uniform base (+lane*16 implicit)
__device__ inline void async16(const void* g, void* l) {
  __builtin_amdgcn_global_load_lds(
      (__attribute__((address_space(1))) void*)(const_cast<void*>(g)),
      (__attribute__((address_space(3))) void*)l, 16, 0, 0);
}

// ===========================================================================
// FAST PATH
// ===========================================================================

// Prep: weight conversions (0..3) + key/value bf16 (4,5) + mask (6) + amask (7)
__global__ __launch_bounds__(256) void convpack(
    const float* __restrict__ Wk, const float* __restrict__ Wv,
    const float* __restrict__ Wq, const float* __restrict__ Wo,
    const float* __restrict__ key, const float* __restrict__ value,
    const int* __restrict__ mask, const int* __restrict__ amask,
    u16* __restrict__ Wkb, u16* __restrict__ Wvb, u16* __restrict__ Wqb,
    u16* __restrict__ Wob, u16* __restrict__ keyb, u16* __restrict__ valb,
    u32* __restrict__ maskb, u32* __restrict__ amaskb) {
  const int job = blockIdx.y;
  const int gtid = blockIdx.x * 256 + threadIdx.x;
  const int stride = gridDim.x * 256;

  if (job < 6) {
    const float* src; u16* dst; size_t n4;
    switch (job) {
      case 0: src = Wk;    dst = Wkb;  n4 = (size_t)DD * DD / 4; break;
      case 1: src = Wv;    dst = Wvb;  n4 = (size_t)DD * DD / 4; break;
      case 2: src = Wq;    dst = Wqb;  n4 = (size_t)DD * DD / 4; break;
      case 3: src = Wo;    dst = Wob;  n4 = (size_t)DD * DD / 4; break;
      case 4: src = key;   dst = keyb; n4 = (size_t)BB * LL * DD / 4; break;
      default: src = value; dst = valb; n4 = (size_t)BB * LL * DD / 4; break;
    }
    for (size_t i = gtid; i < n4; i += stride) {
      float4 v = ((const float4*)src)[i];
      short4v s;
      s[0] = (short)f2b(v.x); s[1] = (short)f2b(v.y);
      s[2] = (short)f2b(v.z); s[3] = (short)f2b(v.w);
      *(short4v*)(dst + i * 4) = s;
    }
  } else if (job == 6) {
    const size_t nw = (size_t)BB * LL * LL / 32;  // 262144 words
    for (size_t w = gtid; w < nw; w += stride) {
      const int4* src = (const int4*)(mask + w * 32);
      u32 bits = 0;
#pragma unroll
      for (int c = 0; c < 8; c++) {
        int4 v = src[c];
        bits |= (u32)(v.x != 0) << (c * 4);
        bits |= (u32)(v.y != 0) << (c * 4 + 1);
        bits |= (u32)(v.z != 0) << (c * 4 + 2);
        bits |= (u32)(v.w != 0) << (c * 4 + 3);
      }
      maskb[w] = bits;
    }
  } else {
    const int nw = BB * LL / 32;  // 256 words
    for (int w = gtid; w < nw; w += stride) {
      const int4* src = (const int4*)(amask + w * 32);
      u32 bits = 0;
#pragma unroll
      for (int c = 0; c < 8; c++) {
        int4 v = src[c];
        bits |= (u32)(v.x != 0) << (c * 4);
        bits |= (u32)(v.y != 0) << (c * 4 + 1);
        bits |= (u32)(v.z != 0) << (c * 4 + 2);
        bits |= (u32)(v.w != 0) << (c * 4 + 3);
      }
      amaskb[w] = bits;
    }
  }
}

// ---------------------------------------------------------------------------
// R8 GEMM structure: BM=256, BN=128, BK=64, 512 threads (8 waves as 4M x 2N),
// per-wave 64x64 output (acc[4][4], proven fragment paths).
// LDS: A 2-buf [256][64] (64KB) + B 3-buf [128][64] (48KB) = 112KB.
// Tiles granule-XOR-swizzled (attn-proven, both-sides): LDS granule g holds
// global col (g&7)^(row&7) -> b128 frag reads land 2 lanes/bank-quad (free).
// Schedule (ledger-verified): A staged at distance 1, B at distance 2;
// ONE barrier + uniform vmcnt(2) per K-tile; 64 MFMA between barriers.
//   prologue: stageA(0); stageB(0); stageB(1)            [queue 8]
//   iter t:   vmcnt(2)  -> retires A(t)+B(t) (oldest; leaves B(t+1))
//             barrier   -> every wave's tile-t loads retired => LDS ready
//             stage A(t+1), B(min(t+2,15))  (dup B15 at t=14 keeps ledger)
//             compute tile t from Al[t&1], Bl[t%3]
// Write-after-read safety: staging into a buffer happens after the barrier
// that proves all waves finished reading its previous tile (reads complete
// before each wave's barrier entry -- lgkm-enforced before its MFMAs).
// ---------------------------------------------------------------------------

// Merged QKV projection: grid (32, 8, 3), z = 0:K 1:V 2:Q.
// z<2: bf16 A (keyb/valb) via pure global_load_lds.  z==2: f32 query
// reg-staged distance-1 (R6-proven pattern) into Al; B pipeline identical.
__global__ __launch_bounds__(512) void gemm_qkv(
    const u16* __restrict__ keyb, const u16* __restrict__ valb,
    const float* __restrict__ query, const u16* __restrict__ Wkb,
    const u16* __restrict__ Wvb, const u16* __restrict__ Wqb,
    const float* __restrict__ bk, const float* __restrict__ bv,
    const float* __restrict__ bq, u16* __restrict__ kbuf,
    u16* __restrict__ vbt, u16* __restrict__ qbuf) {
  __shared__ u16 Al[2][256 * 64];
  __shared__ u16 Bl[3][128 * 64];

  const int z = blockIdx.z;
  const int tid = threadIdx.x;
  const int wave = tid >> 6, lane = tid & 63;
  const int lr = lane & 15, lq = lane >> 4;
  const int row0 = blockIdx.x * 256;
  const int col0 = blockIdx.y * 128;
  const int wm = (wave >> 1) * 64, wn = (wave & 1) * 64;
  const int x7 = lr & 7;

  floatx4 acc[4][4];
#pragma unroll
  for (int i = 0; i < 4; i++)
#pragma unroll
    for (int j = 0; j < 4; j++) acc[i][j] = (floatx4){0.f, 0.f, 0.f, 0.f};

  const u16* Wb = (z == 0) ? Wkb : (z == 1) ? Wvb : Wqb;

  // B staging: 1024 granules, 2 parts of 512
  const int gB0 = tid, gB1 = 512 + tid;
  const int rB0 = gB0 >> 3, cB0 = (gB0 & 7) ^ (rB0 & 7);
  const int rB1 = gB1 >> 3, cB1 = (gB1 & 7) ^ (rB1 & 7);
  const u16* WgP0 = Wb + (size_t)(col0 + rB0) * 1024 + cB0 * 8;
  const u16* WgP1 = Wb + (size_t)(col0 + rB1) * 1024 + cB1 * 8;
  const int ldsB0 = (wave * 64) * 8;
  const int ldsB1 = (512 + wave * 64) * 8;
  auto stageB = [&](int t, int buf) {
    async16(WgP0 + t * 64, &Bl[buf][ldsB0]);
    async16(WgP1 + t * 64, &Bl[buf][ldsB1]);
  };

  // fragment read column offsets (row&7 == lr&7 since wm/wn/mi*16 are 8-mult)
  const int cs0 = ((0 + lq) ^ x7) * 8;   // K-step 0 (k = lq*8+e)
  const int cs1 = ((4 + lq) ^ x7) * 8;   // K-step 1

  auto compute = [&](const u16* As_, const u16* Bs_) {
#pragma unroll
    for (int kh = 0; kh < 2; kh++) {
      const int cs = kh ? cs1 : cs0;
      short8 af[4], wf[4];
#pragma unroll
      for (int mi = 0; mi < 4; mi++)
        af[mi] = *(const short8*)(As_ + (wm + mi * 16 + lr) * 64 + cs);
#pragma unroll
      for (int ni = 0; ni < 4; ni++)
        wf[ni] = *(const short8*)(Bs_ + (wn + ni * 16 + lr) * 64 + cs);
#pragma unroll
      for (int mi = 0; mi < 4; mi++)
#pragma unroll
        for (int ni = 0; ni < 4; ni++)
          acc[mi][ni] = __builtin_amdgcn_mfma_f32_16x16x32_bf16(
              af[mi], wf[ni], acc[mi][ni], 0, 0, 0);
    }
  };

  if (z < 2) {
    const u16* Ab = (z == 0) ? keyb : valb;
    const u16* AgP[4];
    int ldsA[4];
#pragma unroll
    for (int p = 0; p < 4; p++) {
      const int g = p * 512 + tid;
      const int r = g >> 3, c = (g & 7) ^ (r & 7);
      AgP[p] = Ab + (size_t)(row0 + r) * 1024 + c * 8;
      ldsA[p] = (p * 512 + wave * 64) * 8;
    }
    auto stageA = [&](int t, int buf) {
#pragma unroll
      for (int p = 0; p < 4; p++) async16(AgP[p] + t * 64, &Al[buf][ldsA[p]]);
    };

    stageA(0, 0);
    stageB(0, 0);
    stageB(1, 1);

    int b_buf = 2, t3 = 0;
    for (int t = 0; t < 16; t++) {
      asm volatile("s_waitcnt vmcnt(2)" ::: "memory");
      __builtin_amdgcn_s_barrier();
      __builtin_amdgcn_sched_barrier(0);
      if (t < 15) {
        stageA(t + 1, (t + 1) & 1);
        stageB(t + 2 > 15 ? 15 : t + 2, b_buf);
        b_buf = (b_buf == 2) ? 0 : b_buf + 1;
      }
      compute(&Al[t & 1][0], &Bl[t3][0]);
      t3 = (t3 == 2) ? 0 : t3 + 1;
    }
  } else {
    float4 ag[8];
    int gA_r[4], gA_c[4], ldsA[4];
#pragma unroll
    for (int p = 0; p < 4; p++) {
      const int g = p * 512 + tid;
      gA_r[p] = g >> 3;
      gA_c[p] = (g & 7) ^ (gA_r[p] & 7);
      ldsA[p] = g * 8;
    }
    auto loadAq = [&](int t) {
#pragma unroll
      for (int p = 0; p < 4; p++) {
        const float* s =
            query + (size_t)(row0 + gA_r[p]) * 1024 + t * 64 + gA_c[p] * 8;
        ag[2 * p] = *(const float4*)(s);
        ag[2 * p + 1] = *(const float4*)(s + 4);
      }
    };
    auto writeAq = [&](int buf) {
#pragma unroll
      for (int p = 0; p < 4; p++) {
        short8 s8;
        s8[0] = (short)f2b(ag[2 * p].x);     s8[1] = (short)f2b(ag[2 * p].y);
        s8[2] = (short)f2b(ag[2 * p].z);     s8[3] = (short)f2b(ag[2 * p].w);
        s8[4] = (short)f2b(ag[2 * p + 1].x); s8[5] = (short)f2b(ag[2 * p + 1].y);
        s8[6] = (short)f2b(ag[2 * p + 1].z); s8[7] = (short)f2b(ag[2 * p + 1].w);
        *(short8*)(&Al[buf][ldsA[p]]) = s8;
      }
    };

    // prologue: A0 via regs (issued before B so vmcnt(4) retires only A0)
    loadAq(0);
    stageB(0, 0);
    stageB(1, 1);
    asm volatile("s_waitcnt vmcnt(4)" ::: "memory");
    writeAq(0);

    int b_buf = 2, t3 = 0;
    for (int t = 0; t < 16; t++) {
      asm volatile("s_waitcnt lgkmcnt(0)" ::: "memory");  // my A-writes visible
      asm volatile("s_waitcnt vmcnt(2)" ::: "memory");    // retire B(t)
      __builtin_amdgcn_s_barrier();
      __builtin_amdgcn_sched_barrier(0);
      if (t < 15) {
        loadAq(t + 1);                                    // A older than next B
        stageB(t + 2 > 15 ? 15 : t + 2, b_buf);
        b_buf = (b_buf == 2) ? 0 : b_buf + 1;
      }
      compute(&Al[t & 1][0], &Bl[t3][0]);
      if (t < 15) {
        asm volatile("s_waitcnt vmcnt(2)" ::: "memory");  // retire A(t+1),B(t+1)
        writeAq((t + 1) & 1);
      }
      t3 = (t3 == 2) ? 0 : t3 + 1;
    }
  }

  const float scale = (z == 2) ? QSCALE : 1.0f;
  const float* bias = (z == 0) ? bk : (z == 1) ? bv : bq;
  u16* outb = (z == 0) ? kbuf : qbuf;

#pragma unroll
  for (int ni = 0; ni < 4; ni++) {
    const int col = col0 + wn + ni * 16 + lr;
    const float bvv = bias[col];
#pragma unroll
    for (int mi = 0; mi < 4; mi++) {
#pragma unroll
      for (int r = 0; r < 4; r++) {
        const int row = row0 + wm + mi * 16 + lq * 4 + r;
        const float v = (acc[mi][ni][r] + bvv) * scale;
        const int b = row >> 10, l = row & 1023, h = col >> 6, dh = col & 63;
        if (z == 1)
          vbt[((b * HH + h) * DHH + dh) * LL + l] = f2b(v);   // (B,H,DH,L)
        else
          outb[((b * HH + h) * LL + l) * DHH + dh] = f2b(v);  // (B,H,L,DH)
      }
    }
  }
}

// O-projection GEMM: same R8 structure, bf16 A (cbuf), f32 row-major out.
__global__ __launch_bounds__(512) void gemm_o(
    const u16* __restrict__ A, const u16* __restrict__ Wb,
    const float* __restrict__ bias, float* __restrict__ outp) {
  __shared__ u16 Al[2][256 * 64];
  __shared__ u16 Bl[3][128 * 64];

  const int tid = threadIdx.x;
  const int wave = tid >> 6, lane = tid & 63;
  const int lr = lane & 15, lq = lane >> 4;
  const int row0 = blockIdx.x * 256;
  const int col0 = blockIdx.y * 128;
  const int wm = (wave >> 1) * 64, wn = (wave & 1) * 64;
  const int x7 = lr & 7;

  floatx4 acc[4][4];
#pragma unroll
  for (int i = 0; i < 4; i++)
#pragma unroll
    for (int j = 0; j < 4; j++) acc[i][j] = (floatx4){0.f, 0.f, 0.f, 0.f};

  const int gB0 = tid, gB1 = 512 + tid;
  const int rB0 = gB0 >> 3, cB0 = (gB0 & 7) ^ (rB0 & 7);
  const int rB1 = gB1 >> 3, cB1 = (gB1 & 7) ^ (rB1 & 7);
  const u16* WgP0 = Wb + (size_t)(col0 + rB0) * 1024 + cB0 * 8;
  const u16* WgP1 = Wb + (size_t)(col0 + rB1) * 1024 + cB1 * 8;
  const int ldsB0 = (wave * 64) * 8;
  const int ldsB1 = (512 + wave * 64) * 8;

  const u16* AgP[4];
  int ldsA[4];
#pragma unroll
  for (int p = 0; p < 4; p++) {
    const int g = p * 512 + tid;
    const int r = g >> 3, c = (g & 7) ^ (r & 7);
    AgP[p] = A + (size_t)(row0 + r) * 1024 + c * 8;
    ldsA[p] = (p * 512 + wave * 64) * 8;
  }

  auto stageB = [&](int t, int buf) {
    async16(WgP0 + t * 64, &Bl[buf][ldsB0]);
    async16(WgP1 + t * 64, &Bl[buf][ldsB1]);
  };
  auto stageA = [&](int t, int buf) {
#pragma unroll
    for (int p = 0; p < 4; p++) async16(AgP[p] + t * 64, &Al[buf][ldsA[p]]);
  };

  const int cs0 = ((0 + lq) ^ x7) * 8;
  const int cs1 = ((4 + lq) ^ x7) * 8;

  stageA(0, 0);
  stageB(0, 0);
  stageB(1, 1);

  int b_buf = 2, t3 = 0;
  for (int t = 0; t < 16; t++) {
    asm volatile("s_waitcnt vmcnt(2)" ::: "memory");
    __builtin_amdgcn_s_barrier();
    __builtin_amdgcn_sched_barrier(0);
    if (t < 15) {
      stageA(t + 1, (t + 1) & 1);
      stageB(t + 2 > 15 ? 15 : t + 2, b_buf);
      b_buf = (b_buf == 2) ? 0 : b_buf + 1;
    }
    {
      const u16* As_ = &Al[t & 1][0];
      const u16* Bs_ = &Bl[t3][0];
#pragma unroll
      for (int kh = 0; kh < 2; kh++) {
        const int cs = kh ? cs1 : cs0;
        short8 af[4], wf[4];
#pragma unroll
        for (int mi = 0; mi < 4; mi++)
          af[mi] = *(const short8*)(As_ + (wm + mi * 16 + lr) * 64 + cs);
#pragma unroll
        for (int ni = 0; ni < 4; ni++)
          wf[ni] = *(const short8*)(Bs_ + (wn + ni * 16 + lr) * 64 + cs);
#pragma unroll
        for (int mi = 0; mi < 4; mi++)
#pragma unroll
          for (int ni = 0; ni < 4; ni++)
            acc[mi][ni] = __builtin_amdgcn_mfma_f32_16x16x32_bf16(
                af[mi], wf[ni], acc[mi][ni], 0, 0, 0);
      }
    }
    t3 = (t3 == 2) ? 0 : t3 + 1;
  }

#pragma unroll
  for (int ni = 0; ni < 4; ni++) {
    const int col = col0 + wn + ni * 16 + lr;
    const float bv = bias[col];
#pragma unroll
    for (int mi = 0; mi < 4; mi++) {
#pragma unroll
      for (int r = 0; r < 4; r++) {
        const int row = row0 + wm + mi * 16 + lq * 4 + r;
        outp[(size_t)row * 1024 + col] = acc[mi][ni][r] + bv;
      }
    }
  }
}

// top_score kernel (R7-proven, unchanged): top[b] = (K0 . Q0^T) * ln2
__global__ __launch_bounds__(256) void top_kernel(
    const u16* __restrict__ qbuf, const u16* __restrict__ kbuf,
    float* __restrict__ top) {
  __shared__ u16 Qs[128 * 64];
  __shared__ u16 Ks[128 * 64];

  const int kt = blockIdx.x, qt = blockIdx.y, b = blockIdx.z;
  const int tid = threadIdx.x, wave = tid >> 6, lane = tid & 63;
  const int lr = lane & 15, lq = lane >> 4;
  const int lq4 = lq * 4;
  const int x7 = lr & 7;

  const u16* Qg = qbuf + (size_t)((b * HH + 0) * LL + qt * 128) * DHH;
  const u16* Kg = kbuf + (size_t)((b * HH + 0) * LL + kt * 128) * DHH;

#pragma unroll
  for (int rnd = 0; rnd < 4; rnd++) {
    const int g = rnd * 256 + tid;
    const int row = g >> 3, col = (g & 7) ^ (row & 7);
    async16(Qg + row * 64 + col * 8, Qs + (rnd * 256 + wave * 64) * 8);
    async16(Kg + row * 64 + col * 8, Ks + (rnd * 256 + wave * 64) * 8);
  }
  __syncthreads();

  const int cs0 = ((0 + lq) ^ x7) * 8;
  const int cs1 = ((4 + lq) ^ x7) * 8;

  short8 qf[2][2];
#pragma unroll
  for (int mi = 0; mi < 2; mi++) {
    qf[mi][0] = *(const short8*)(Qs + (wave * 32 + mi * 16 + lr) * 64 + cs0);
    qf[mi][1] = *(const short8*)(Qs + (wave * 32 + mi * 16 + lr) * 64 + cs1);
  }

#pragma unroll
  for (int nj = 0; nj < 8; nj++) {
    const short8 kf0 = *(const short8*)(Ks + (nj * 16 + lr) * 64 + cs0);
    const short8 kf1 = *(const short8*)(Ks + (nj * 16 + lr) * 64 + cs1);
#pragma unroll
    for (int mi = 0; mi < 2; mi++) {
      floatx4 z = (floatx4){0.f, 0.f, 0.f, 0.f};
      z = __builtin_amdgcn_mfma_f32_16x16x32_bf16(kf1, qf[mi][1], z, 0, 0, 0);
      z = __builtin_amdgcn_mfma_f32_16x16x32_bf16(kf0, qf[mi][0], z, 0, 0, 0);
      const int row = qt * 128 + wave * 32 + mi * 16 + lr;
      float4 t;
      t.x = z[0] * LN2F; t.y = z[1] * LN2F;
      t.z = z[2] * LN2F; t.w = z[3] * LN2F;
      *(float4*)(top + (size_t)(b * LL + row) * LL + kt * 128 + nj * 16 + lq4) = t;
    }
  }
}

// Flash attention (R7-proven, unchanged).
__global__ __launch_bounds__(256) void attn_fast(
    const u16* __restrict__ qbuf, const u16* __restrict__ kbuf,
    const u16* __restrict__ vbt, const u32* __restrict__ maskb,
    const u32* __restrict__ amaskb, u16* __restrict__ ctx) {
  __shared__ u16 Ks[2][64 * 64];
  __shared__ u16 Vts[2][64 * 64];   // [dh][key], granule-swizzled

  const int id = blockIdx.x;
  const int xcd = id & 7;
  const int r_ = id >> 3;
  const int b = r_ & 7;
  const int h = (((r_ >> 3) & 1) << 3) | (xcd ^ b);
  const int qt = r_ >> 4;

  const int tid = threadIdx.x, wave = tid >> 6, lane = tid & 63;
  const int lr = lane & 15, lq = lane >> 4;
  const int lq4 = lq * 4;
  const int x7 = lr & 7;

  const u16* Qg = qbuf + (size_t)((b * HH + h) * LL + qt * 128) * DHH;
  const u16* Kg = kbuf + (size_t)((b * HH + h) * LL) * DHH;
  const u16* Vtg = vbt + (size_t)((b * HH + h) * DHH) * LL;  // [dh][l]

  short8 qf[2][2];
#pragma unroll
  for (int mi = 0; mi < 2; mi++)
#pragma unroll
    for (int kk = 0; kk < 2; kk++)
      qf[mi][kk] = *(const short8*)(Qg + (wave * 32 + mi * 16 + lr) * 64 +
                                    kk * 32 + lq * 8);

  const int g0 = tid, g1 = 256 + tid;
  const int kr0 = g0 >> 3, kc0 = (g0 & 7) ^ (kr0 & 7);
  const int kr1 = g1 >> 3, kc1 = (g1 & 7) ^ (kr1 & 7);
  const int cs0 = ((0 + lq) ^ x7) * 8;
  const int cs1 = ((4 + lq) ^ x7) * 8;
  const int lqh = lq >> 1, lqb = (lq & 1) * 4;
  const int go00 = ((0 + lqh) ^ x7) * 8 + lqb;  // kk=0 lo
  const int go01 = ((2 + lqh) ^ x7) * 8 + lqb;  // kk=0 hi
  const int go10 = ((4 + lqh) ^ x7) * 8 + lqb;  // kk=1 lo
  const int go11 = ((6 + lqh) ^ x7) * 8 + lqb;  // kk=1 hi

  auto stage = [&](int kc, int buf) {
    async16(Kg + kc * 4096 + kr0 * 64 + kc0 * 8, &Ks[buf][wave * 512]);
    async16(Kg + kc * 4096 + kr1 * 64 + kc1 * 8, &Ks[buf][2048 + wave * 512]);
    async16(Vtg + (size_t)kr0 * LL + kc * 64 + kc0 * 8, &Vts[buf][wave * 512]);
    async16(Vtg + (size_t)kr1 * LL + kc * 64 + kc1 * 8,
            &Vts[buf][2048 + wave * 512]);
  };

  const int rowm0 = qt * 128 + wave * 32 + lr;         // mi=0 row
  const int rowm1 = rowm0 + 16;                        // mi=1 row
  const u32* mb0 = (h < 8) ? maskb + (size_t)(b * LL + rowm0) * 32
                           : amaskb + b * 32;
  const u32* mb1 = (h < 8) ? maskb + (size_t)(b * LL + rowm1) * 32
                           : amaskb + b * 32;
  uint2 mwc0 = *(const uint2*)(mb0);
  uint2 mwc1 = *(const uint2*)(mb1);

  float mrow[2], lrow[2];
  floatx4 Oacc[2][4];
#pragma unroll
  for (int mi = 0; mi < 2; mi++) {
    mrow[mi] = NEGBIG;
    lrow[mi] = 0.f;
#pragma unroll
    for (int ni = 0; ni < 4; ni++) Oacc[mi][ni] = (floatx4){0.f, 0.f, 0.f, 0.f};
  }

  stage(0, 0);

  for (int kc = 0; kc < 16; kc++) {
    const int cur = kc & 1;
    __syncthreads();
    uint2 mwn0, mwn1;
    if (kc < 15) {
      stage(kc + 1, cur ^ 1);
      mwn0 = *(const uint2*)(mb0 + (kc + 1) * 2);   // in flight during compute
      mwn1 = *(const uint2*)(mb1 + (kc + 1) * 2);
    }
    const u16* Ksc = Ks[cur];
    const u16* Vtsc = Vts[cur];

    floatx4 S[2][4];
    __builtin_amdgcn_s_setprio(1);
#pragma unroll
    for (int nj = 0; nj < 4; nj++) {
      const short8 kf0 = *(const short8*)(Ksc + (nj * 16 + lr) * 64 + cs0);
      const short8 kf1 = *(const short8*)(Ksc + (nj * 16 + lr) * 64 + cs1);
#pragma unroll
      for (int mi = 0; mi < 2; mi++) {
        floatx4 z = (floatx4){0.f, 0.f, 0.f, 0.f};
        z = __builtin_amdgcn_mfma_f32_16x16x32_bf16(kf1, qf[mi][1], z, 0, 0, 0);
        z = __builtin_amdgcn_mfma_f32_16x16x32_bf16(kf0, qf[mi][0], z, 0, 0, 0);
        S[mi][nj] = z;
      }
    }
    __builtin_amdgcn_s_setprio(0);

    short8 pf[2][2];
#pragma unroll
    for (int mi = 0; mi < 2; mi++) {
      {
        const uint2 mw = mi ? mwc1 : mwc0;
#pragma unroll
        for (int nj = 0; nj < 4; nj++) {
          const u32 nib = (((nj & 2) ? mw.y : mw.x) >> ((nj & 1) * 16 + lq4)) & 15u;
#pragma unroll
          for (int r = 0; r < 4; r++)
            if ((nib >> r) & 1) S[mi][nj][r] = -1e18f;
        }
      }

      // online softmax (exp2 domain) with defer-max (T13)
      float cm = fmaxf(fmaxf(S[mi][0][0], S[mi][0][1]),
                       fmaxf(S[mi][0][2], S[mi][0][3]));
#pragma unroll
      for (int nj = 1; nj < 4; nj++)
        cm = fmaxf(cm, fmaxf(fmaxf(S[mi][nj][0], S[mi][nj][1]),
                             fmaxf(S[mi][nj][2], S[mi][nj][3])));
      cm = fmaxf(cm, __shfl_xor(cm, 16, 64));
      cm = fmaxf(cm, __shfl_xor(cm, 32, 64));
      const float mold = mrow[mi];
      if (!__all(cm <= mold + DEFER_THR)) {
        const float mnew = fmaxf(mold, cm);
        const float alpha = fexp2(mold - mnew);
        mrow[mi] = mnew;
        lrow[mi] *= alpha;
#pragma unroll
        for (int ni = 0; ni < 4; ni++)
#pragma unroll
          for (int r = 0; r < 4; r++) Oacc[mi][ni][r] *= alpha;
      }
      const float mcur = mrow[mi];
      float rs = 0.f;
#pragma unroll
      for (int nj = 0; nj < 4; nj++)
#pragma unroll
        for (int r = 0; r < 4; r++) {
          const float p = fexp2(S[mi][nj][r] - mcur);
          S[mi][nj][r] = p;
          rs += p;
        }
      rs += __shfl_xor(rs, 16, 64);
      rs += __shfl_xor(rs, 32, 64);
      lrow[mi] += rs;

      // P fragment under key-relabeling kappa (R2-proven)
#pragma unroll
      for (int kk = 0; kk < 2; kk++) {
        short8 p;
#pragma unroll
        for (int r = 0; r < 4; r++) {
          p[r] = (short)f2b(S[mi][2 * kk][r]);
          p[4 + r] = (short)f2b(S[mi][2 * kk + 1][r]);
        }
        pf[mi][kk] = p;
      }
    }

    __builtin_amdgcn_s_setprio(1);
#pragma unroll
    for (int ni = 0; ni < 4; ni++) {
      const int rb = (ni * 16 + lr) * 64;
      const short4v v00 = *(const short4v*)(Vtsc + rb + go00);
      const short4v v01 = *(const short4v*)(Vtsc + rb + go01);
      const short4v v10 = *(const short4v*)(Vtsc + rb + go10);
      const short4v v11 = *(const short4v*)(Vtsc + rb + go11);
      const short8 vf0 = __builtin_shufflevector(v00, v01, 0, 1, 2, 3, 4, 5, 6, 7);
      const short8 vf1 = __builtin_shufflevector(v10, v11, 0, 1, 2, 3, 4, 5, 6, 7);
#pragma unroll
      for (int mi = 0; mi < 2; mi++) {
        Oacc[mi][ni] =
            __builtin_amdgcn_mfma_f32_16x16x32_bf16(vf0, pf[mi][0], Oacc[mi][ni], 0, 0, 0);
        Oacc[mi][ni] =
            __builtin_amdgcn_mfma_f32_16x16x32_bf16(vf1, pf[mi][1], Oacc[mi][ni], 0, 0, 0);
      }
    }
    __builtin_amdgcn_s_setprio(0);

    if (kc < 15) { mwc0 = mwn0; mwc1 = mwn1; }
  }

#pragma unroll
  for (int mi = 0; mi < 2; mi++) {
    const float inv = 1.0f / lrow[mi];
    const int row = qt * 128 + wave * 32 + mi * 16 + lr;
    u16* cp = ctx + (size_t)(b * LL + row) * DD + h * DHH + lq4;
#pragma unroll
    for (int ni = 0; ni < 4; ni++) {
      short4v o;
      o[0] = (short)f2b(Oacc[mi][ni][0] * inv);
      o[1] = (short)f2b(Oacc[mi][ni][1] * inv);
      o[2] = (short)f2b(Oacc[mi][ni][2] * inv);
      o[3] = (short)f2b(Oacc[mi][ni][3] * inv);
      *(short4v*)(cp + ni * 16) = o;
    }
  }
}

// ===========================================================================
// FALLBACK PATH (R5-proven, 64 MB ws)
// ===========================================================================
template <int MODE>
__global__ __launch_bounds__(256) void gemm_k(
    const void* __restrict__ Av, const float* __restrict__ W,
    const float* __restrict__ biasp, void* __restrict__ outv, float scale) {
  __shared__ u16 As[128 * 32];
  __shared__ u16 Ws[128 * 32];
  const int tid = threadIdx.x;
  const int wave = tid >> 6, lane = tid & 63;
  const int lr = lane & 15, lq = lane >> 4;
  const int row0 = blockIdx.x * 128;
  const int col0 = blockIdx.y * 128;
  const int wm = (wave & 1) * 64, wn = (wave >> 1) * 64;
  floatx4 acc[4][4];
#pragma unroll
  for (int i = 0; i < 4; i++)
#pragma unroll
    for (int j = 0; j < 4; j++) acc[i][j] = (floatx4){0.f, 0.f, 0.f, 0.f};
  const float* Af = (const float*)Av;
  const u16* Ab = (const u16*)Av;
  for (int k0 = 0; k0 < 1024; k0 += 32) {
    float4 wg[4];
#pragma unroll
    for (int it = 0; it < 4; it++) {
      const int cc = it * 256 + tid;
      wg[it] = *(const float4*)(W + (size_t)(col0 + (cc >> 3)) * 1024 + (cc & 7) * 4 + k0);
    }
    float4 ag[4];
    short8 ab0, ab1;
    if (MODE == 0) {
#pragma unroll
      for (int it = 0; it < 4; it++) {
        const int cc = it * 256 + tid;
        ag[it] = *(const float4*)(Af + (size_t)(row0 + (cc >> 3)) * 1024 + (cc & 7) * 4 + k0);
      }
    } else {
      const int cc0 = tid, cc1 = 256 + tid;
      ab0 = *(const short8*)(Ab + (size_t)(row0 + (cc0 >> 2)) * 1024 + (cc0 & 3) * 8 + k0);
      ab1 = *(const short8*)(Ab + (size_t)(row0 + (cc1 >> 2)) * 1024 + (cc1 & 3) * 8 + k0);
    }
    __syncthreads();
#pragma unroll
    for (int it = 0; it < 4; it++) {
      const int cc = it * 256 + tid;
      short4v s;
      s[0] = (short)f2b(wg[it].x); s[1] = (short)f2b(wg[it].y);
      s[2] = (short)f2b(wg[it].z); s[3] = (short)f2b(wg[it].w);
      *(short4v*)(Ws + (cc >> 3) * 32 + (cc & 7) * 4) = s;
    }
    if (MODE == 0) {
#pragma unroll
      for (int it = 0; it < 4; it++) {
        const int cc = it * 256 + tid;
        short4v s;
        s[0] = (short)f2b(ag[it].x); s[1] = (short)f2b(ag[it].y);
        s[2] = (short)f2b(ag[it].z); s[3] = (short)f2b(ag[it].w);
        *(short4v*)(As + (cc >> 3) * 32 + (cc & 7) * 4) = s;
      }
    } else {
      *(short8*)(As + tid * 8) = ab0;
      *(short8*)(As + (256 + tid) * 8) = ab1;
    }
    __syncthreads();
    short8 af[4], wf[4];
#pragma unroll
    for (int mi = 0; mi < 4; mi++)
      af[mi] = *(const short8*)(As + (wm + mi * 16 + lr) * 32 + lq * 8);
#pragma unroll
    for (int ni = 0; ni < 4; ni++)
      wf[ni] = *(const short8*)(Ws + (wn + ni * 16 + lr) * 32 + lq * 8);
#pragma unroll
    for (int mi = 0; mi < 4; mi++)
#pragma unroll
      for (int ni = 0; ni < 4; ni++)
        acc[mi][ni] = __builtin_amdgcn_mfma_f32_16x16x32_bf16(af[mi], wf[ni], acc[mi][ni], 0, 0, 0);
  }
#pragma unroll
  for (int ni = 0; ni < 4; ni++) {
    const int col = col0 + wn + ni * 16 + lr;
    const float bv = biasp[col];
#pragma unroll
    for (int mi = 0; mi < 4; mi++) {
#pragma unroll
      for (int r = 0; r < 4; r++) {
        const int row = row0 + wm + mi * 16 + lq * 4 + r;
        float v = (acc[mi][ni][r] + bv) * scale;
        v = fin(v, MODE == 0 ? 700.0f : 1000.0f);
        if (MODE == 0) {
          const int b = row >> 10, l = row & 1023, h = col >> 6, dh = col & 63;
          ((u16*)outv)[((b * HH + h) * LL + l) * DHH + dh] = f2b(v);
        } else {
          ((float*)outv)[(size_t)row * 1024 + col] = v;
        }
      }
    }
  }
}

__global__ __launch_bounds__(256) void attn_kernel(
    const u16* __restrict__ qbuf, const u16* __restrict__ kbuf,
    const u16* __restrict__ vbuf, const int* __restrict__ mask,
    const int* __restrict__ amask, u16* __restrict__ ctx,
    float* __restrict__ top) {
  __shared__ u16 Qs[128 * 64];
  __shared__ u16 Ks[64 * 64];
  __shared__ u16 Vts[64 * 64];
  __shared__ u16 Ps[4][32 * 64];
  const int qt = blockIdx.x, h = blockIdx.y, b = blockIdx.z;
  const int tid = threadIdx.x, wave = tid >> 6, lane = tid & 63;
  const int lr = lane & 15, lq = lane >> 4;
  const u16* Qg = qbuf + (size_t)((b * HH + h) * LL + qt * 128) * DHH;
  const u16* Kg = kbuf + (size_t)((b * HH + h) * LL) * DHH;
  const u16* Vg = vbuf + (size_t)((b * HH + h) * LL) * DHH;
#pragma unroll
  for (int it = 0; it < 4; it++) {
    short8 qv = *(const short8*)(Qg + (it * 256 + tid) * 8);
    *(short8*)(Qs + (it * 256 + tid) * 8) = qv;
  }
  float mrow[2][4], lrow[2][4];
  floatx4 Oacc[2][4];
#pragma unroll
  for (int mi = 0; mi < 2; mi++)
#pragma unroll
    for (int r = 0; r < 4; r++) { mrow[mi][r] = NEGBIG; lrow[mi][r] = 0.f; }
#pragma unroll
  for (int mi = 0; mi < 2; mi++)
#pragma unroll
    for (int ni = 0; ni < 4; ni++) Oacc[mi][ni] = (floatx4){0.f, 0.f, 0.f, 0.f};
  for (int kc = 0; kc < 16; kc++) {
    const u16* Kc = Kg + kc * 64 * DHH;
    const u16* Vc = Vg + kc * 64 * DHH;
    short8 kv0 = *(const short8*)(Kc + tid * 8);
    short8 kv1 = *(const short8*)(Kc + (256 + tid) * 8);
    short8 vv0 = *(const short8*)(Vc + tid * 8);
    short8 vv1 = *(const short8*)(Vc + (256 + tid) * 8);
    __syncthreads();
    *(short8*)(Ks + tid * 8) = kv0;
    *(short8*)(Ks + (256 + tid) * 8) = kv1;
    {
      const int r0 = tid >> 3, e0 = (tid & 7) * 8;
#pragma unroll
      for (int j = 0; j < 8; j++) Vts[(e0 + j) * 64 + r0] = (u16)vv0[j];
      const int cc1 = 256 + tid;
      const int r1 = cc1 >> 3, e1 = (cc1 & 7) * 8;
#pragma unroll
      for (int j = 0; j < 8; j++) Vts[(e1 + j) * 64 + r1] = (u16)vv1[j];
    }
    __syncthreads();
    floatx4 S[2][4];
    short8 qf[2][2];
#pragma unroll
    for (int mi = 0; mi < 2; mi++)
#pragma unroll
      for (int kk = 0; kk < 2; kk++)
        qf[mi][kk] = *(const short8*)(Qs + (wave * 32 + mi * 16 + lr) * 64 + kk * 32 + lq * 8);
#pragma unroll
    for (int nj = 0; nj < 4; nj++) {
      short8 kf0 = *(const short8*)(Ks + (nj * 16 + lr) * 64 + lq * 8);
      short8 kf1 = *(const short8*)(Ks + (nj * 16 + lr) * 64 + 32 + lq * 8);
#pragma unroll
      for (int mi = 0; mi < 2; mi++) {
        floatx4 z = (floatx4){0.f, 0.f, 0.f, 0.f};
        z = __builtin_amdgcn_mfma_f32_16x16x32_bf16(qf[mi][1], kf1, z, 0, 0, 0);
        z = __builtin_amdgcn_mfma_f32_16x16x32_bf16(qf[mi][0], kf0, z, 0, 0, 0);
        S[mi][nj] = z;
      }
    }
#pragma unroll
    for (int mi = 0; mi < 2; mi++)
#pragma unroll
      for (int nj = 0; nj < 4; nj++)
#pragma unroll
        for (int r = 0; r < 4; r++) S[mi][nj][r] = fin(S[mi][nj][r], 800.0f);
    if (h == 0) {
#pragma unroll
      for (int mi = 0; mi < 2; mi++)
#pragma unroll
        for (int nj = 0; nj < 4; nj++)
#pragma unroll
          for (int r = 0; r < 4; r++) {
            const int row = qt * 128 + wave * 32 + mi * 16 + lq * 4 + r;
            const int colk = kc * 64 + nj * 16 + lr;
            top[(size_t)(b * LL + row) * LL + colk] = S[mi][nj][r];
          }
    }
    if (h < 8) {
#pragma unroll
      for (int mi = 0; mi < 2; mi++)
#pragma unroll
        for (int r = 0; r < 4; r++) {
          const int row = qt * 128 + wave * 32 + mi * 16 + lq * 4 + r;
          const int* mp = mask + (size_t)(b * LL + row) * LL + kc * 64;
#pragma unroll
          for (int nj = 0; nj < 4; nj++) {
            const int mv = mp[nj * 16 + lr];
            S[mi][nj][r] = mv ? -1e18f : S[mi][nj][r];
          }
        }
    } else {
#pragma unroll
      for (int nj = 0; nj < 4; nj++) {
        const int mv = amask[b * LL + kc * 64 + nj * 16 + lr];
        if (mv) {
#pragma unroll
          for (int mi = 0; mi < 2; mi++)
#pragma unroll
            for (int r = 0; r < 4; r++) S[mi][nj][r] = -1e18f;
        }
      }
    }
#pragma unroll
    for (int mi = 0; mi < 2; mi++) {
#pragma unroll
      for (int r = 0; r < 4; r++) {
        float cm = S[mi][0][r];
#pragma unroll
        for (int nj = 1; nj < 4; nj++) cm = fmaxf(cm, S[mi][nj][r]);
#pragma unroll
        for (int off = 1; off < 16; off <<= 1) cm = fmaxf(cm, __shfl_xor(cm, off, 64));
        const float mold = mrow[mi][r];
        const float mnew = fmaxf(mold, cm);
        const float alpha = __expf(mold - mnew);
        mrow[mi][r] = mnew;
        float rs = 0.f;
#pragma unroll
        for (int nj = 0; nj < 4; nj++) {
          const float p = __expf(S[mi][nj][r] - mnew);
          S[mi][nj][r] = p;
          rs += p;
        }
#pragma unroll
        for (int off = 1; off < 16; off <<= 1) rs += __shfl_xor(rs, off, 64);
        lrow[mi][r] = lrow[mi][r] * alpha + rs;
#pragma unroll
        for (int ni = 0; ni < 4; ni++) Oacc[mi][ni][r] *= alpha;
      }
    }
#pragma unroll
    for (int mi = 0; mi < 2; mi++)
#pragma unroll
      for (int nj = 0; nj < 4; nj++)
#pragma unroll
        for (int r = 0; r < 4; r++)
          Ps[wave][(mi * 16 + lq * 4 + r) * 64 + nj * 16 + lr] = f2b(S[mi][nj][r]);
    __syncthreads();
#pragma unroll
    for (int kk = 0; kk < 2; kk++) {
      short8 pf[2];
#pragma unroll
      for (int mi = 0; mi < 2; mi++)
        pf[mi] = *(const short8*)(&Ps[wave][(mi * 16 + lr) * 64 + kk * 32 + lq * 8]);
#pragma unroll
      for (int ni = 0; ni < 4; ni++) {
        short8 vf = *(const short8*)(Vts + (ni * 16 + lr) * 64 + kk * 32 + lq * 8);
#pragma unroll
        for (int mi = 0; mi < 2; mi++)
          Oacc[mi][ni] = __builtin_amdgcn_mfma_f32_16x16x32_bf16(pf[mi], vf, Oacc[mi][ni], 0, 0, 0);
      }
    }
  }
#pragma unroll
  for (int mi = 0; mi < 2; mi++)
#pragma unroll
    for (int r = 0; r < 4; r++) {
      const float inv = 1.0f / lrow[mi][r];
      const int row = qt * 128 + wave * 32 + mi * 16 + lq * 4 + r;
#pragma unroll
      for (int ni = 0; ni < 4; ni++) {
        const int col = h * DHH + ni * 16 + lr;
        ctx[(size_t)(b * LL + row) * DD + col] = f2b(fin(Oacc[mi][ni][r] * inv, 900.0f));
      }
    }
}

// ===========================================================================
extern "C" void kernel_launch(void* const* d_in, const int* in_sizes, int n_in,
                              void* d_out, int out_size, void* d_ws, size_t ws_size,
                              hipStream_t stream) {
  const float* key   = (const float*)d_in[0];
  const float* value = (const float*)d_in[1];
  const float* query = (const float*)d_in[2];
  const int* mask    = (const int*)d_in[3];
  const int* amask   = (const int*)d_in[4];
  const float* Wk = (const float*)d_in[5];
  const float* bk = (const float*)d_in[6];
  const float* Wv = (const float*)d_in[7];
  const float* bv = (const float*)d_in[8];
  const float* Wq = (const float*)d_in[9];
  const float* bq = (const float*)d_in[10];
  const float* Wo = (const float*)d_in[11];
  const float* bo = (const float*)d_in[12];

  float* outp = (float*)d_out;                  // out (B,L,D) f32
  float* topp = outp + (size_t)BB * LL * DD;    // top_score (B,L,L) f32

  const size_t M8 = (size_t)BB * LL * DD;       // 8M elems
  const size_t M1 = (size_t)DD * DD;            // 1M elems
  const size_t NEED = (size_t)90 * 1024 * 1024; // fast-path ws bytes (= layout)

  dim3 tb(256), gg(64, 8, 1), ga(8, 16, 8);

  if (ws_size >= NEED) {
    // Layout (u16 units), total exactly 5*M8 + 5*M1 = 90 MB:
    //   keyb @0 (M8)  [dead after gemm_qkv; reused as cbuf by attn]
    //   valb @M8 (M8)
    //   Wkb..Wob @2*M8 (4*M1)
    //   maskb/amaskb @2*M8+4*M1 (fits in 1*M1)
    //   kbuf @2*M8+5*M1, vbt +M8, qbuf +2*M8
    u16* W16 = (u16*)d_ws;
    u16* keyb = W16;
    u16* valb = W16 + M8;
    u16* Wkb = W16 + 2 * M8;
    u16* Wvb = Wkb + M1;
    u16* Wqb = Wvb + M1;
    u16* Wob = Wqb + M1;
    u32* maskb = (u32*)(Wob + M1);
    u32* amaskb = maskb + 262144;
    u16* kbuf = W16 + 2 * M8 + 5 * M1;
    u16* vbt  = kbuf + M8;
    u16* qbuf = vbt + M8;
    u16* cbuf = keyb;

    convpack<<<dim3(256, 8), tb, 0, stream>>>(
        Wk, Wv, Wq, Wo, key, value, mask, amask,
        Wkb, Wvb, Wqb, Wob, keyb, valb, maskb, amaskb);
    gemm_qkv<<<dim3(32, 8, 3), dim3(512), 0, stream>>>(
        keyb, valb, query, Wkb, Wvb, Wqb, bk, bv, bq, kbuf, vbt, qbuf);
    top_kernel<<<dim3(8, 8, 8), tb, 0, stream>>>(qbuf, kbuf, topp);
    attn_fast<<<dim3(1024, 1, 1), tb, 0, stream>>>(qbuf, kbuf, vbt, maskb,
                                                   amaskb, cbuf);
    gemm_o<<<dim3(32, 8, 1), dim3(512), 0, stream>>>(cbuf, Wob, bo, outp);
  } else {
    u16* kbuf = (u16*)d_ws;
    u16* vbuf = kbuf + M8;
    u16* qbuf = vbuf + M8;
    u16* cbuf = qbuf + M8;
    gemm_k<0><<<gg, tb, 0, stream>>>(key,   Wk, bk, kbuf, 1.0f);
    gemm_k<0><<<gg, tb, 0, stream>>>(value, Wv, bv, vbuf, 1.0f);
    gemm_k<0><<<gg, tb, 0, stream>>>(query, Wq, bq, qbuf, 0.125f);
    attn_kernel<<<ga, tb, 0, stream>>>(qbuf, kbuf, vbuf, mask, amask, cbuf, topp);
    gemm_k<1><<<gg, tb, 0, stream>>>(cbuf, Wo, bo, outp, 1.0f);
  }
}

// Round 9
// 408.105 us; speedup vs baseline: 1.0165x; 1.0165x over previous
//
#include <hip/hip_runtime.h>
#include <hip/hip_bf16.h>

typedef unsigned short u16;
typedef unsigned int u32;
typedef __attribute__((ext_vector_type(8))) short short8;   // 8 bf16 MFMA frag
typedef __attribute__((ext_vector_type(4))) short short4v;  // 4 bf16
typedef __attribute__((ext_vector_type(4))) float floatx4;  // MFMA C/D frag

#define BB 8
#define LL 1024
#define DD 1024
#define HH 16
#define DHH 64
#define NEGBIG (-3.0e38f)
// q pre-scale folds log2e so softmax uses native v_exp_f32 (2^x): exact transform.
#define QSCALE 0.1803368801111204f   // 0.125 * log2(e)
#define LN2F   0.6931471805599453f   // top = S' * ln2 recovers raw scores
#define DEFER_THR 12.0f              // defer-max threshold (log2 domain): P <= 2^12

__device__ inline u16 f2b(float f) {
  union { __hip_bfloat16 h; u16 u; } cv;
  cv.h = __float2bfloat16(f);  // RNE
  return cv.u;
}
__device__ inline float b2f(u16 u) {
  union { u16 u; __hip_bfloat16 h; } cv;
  cv.u = u;
  return __bfloat162float(cv.h);
}
__device__ inline float fin(float v, float sentinel) {
  return (fabsf(v) < 1e30f) ? v : sentinel;
}
__device__ inline float fexp2(float x) {
#if __has_builtin(__builtin_amdgcn_exp2f)
  return __builtin_amdgcn_exp2f(x);
#else
  return exp2f(x);
#endif
}
// async global->LDS, 16B/lane; LDS dst = wave-uniform base (+lane*16 implicit)
__device__ inline void async16(const void* g, void* l) {
  __builtin_amdgcn_global_load_lds(
      (__attribute__((address_space(1))) void*)(const_cast<void*>(g)),
      (__attribute__((address_space(3))) void*)l, 16, 0, 0);
}

// ===========================================================================
// FAST PATH
// ===========================================================================

// Weights-only conversion (masks fold into gemm_qkv z==3 now).
__global__ __launch_bounds__(256) void convpack_w(
    const float* __restrict__ Wk, const float* __restrict__ Wv,
    const float* __restrict__ Wq, const float* __restrict__ Wo,
    u16* __restrict__ Wkb, u16* __restrict__ Wvb, u16* __restrict__ Wqb,
    u16* __restrict__ Wob) {
  const int job = blockIdx.y;
  const int gtid = blockIdx.x * 256 + threadIdx.x;
  const int stride = gridDim.x * 256;
  const float* src; u16* dst;
  switch (job) {
    case 0: src = Wk; dst = Wkb; break;
    case 1: src = Wv; dst = Wvb; break;
    case 2: src = Wq; dst = Wqb; break;
    default: src = Wo; dst = Wob; break;
  }
  const size_t n4 = (size_t)DD * DD / 4;
  for (size_t i = gtid; i < n4; i += stride) {
    float4 v = ((const float4*)src)[i];
    short4v s;
    s[0] = (short)f2b(v.x); s[1] = (short)f2b(v.y);
    s[2] = (short)f2b(v.z); s[3] = (short)f2b(v.w);
    *(short4v*)(dst + i * 4) = s;
  }
}

// Merged QKV projection GEMM (R6-proven deep-issue pipeline) + z==3 = mask
// bit-pack blocks riding under the latency-bound GEMM (spare BW at 11% HBM).
// grid (64, 8, 4): z = 0:K 1:V 2:Q 3:maskpack.
__global__ __launch_bounds__(256) void gemm_qkv(
    const float* __restrict__ key, const float* __restrict__ value,
    const float* __restrict__ query, const u16* __restrict__ Wkb,
    const u16* __restrict__ Wvb, const u16* __restrict__ Wqb,
    const float* __restrict__ bk, const float* __restrict__ bv,
    const float* __restrict__ bq, const int* __restrict__ mask,
    const int* __restrict__ amask, u16* __restrict__ kbuf,
    u16* __restrict__ vbt, u16* __restrict__ qbuf,
    u32* __restrict__ maskb, u32* __restrict__ amaskb) {
  __shared__ u16 As[2][128 * 32];
  __shared__ u16 Ws[3][128 * 32];

  const int z = blockIdx.z;
  const int tid = threadIdx.x;

  if (z == 3) {  // mask bit-pack: 512 blocks, grid-stride
    const int flat = blockIdx.y * 64 + blockIdx.x;   // 0..511
    const int gtid = flat * 256 + tid;
    const int stride = 512 * 256;
    const size_t nw = (size_t)BB * LL * LL / 32;     // 262144 words
    for (size_t w = gtid; w < nw; w += stride) {
      const int4* src = (const int4*)(mask + w * 32);
      u32 bits = 0;
#pragma unroll
      for (int c = 0; c < 8; c++) {
        int4 v = src[c];
        bits |= (u32)(v.x != 0) << (c * 4);
        bits |= (u32)(v.y != 0) << (c * 4 + 1);
        bits |= (u32)(v.z != 0) << (c * 4 + 2);
        bits |= (u32)(v.w != 0) << (c * 4 + 3);
      }
      maskb[w] = bits;
    }
    if (gtid < BB * LL / 32) {  // 256 words
      const int4* src = (const int4*)(amask + gtid * 32);
      u32 bits = 0;
#pragma unroll
      for (int c = 0; c < 8; c++) {
        int4 v = src[c];
        bits |= (u32)(v.x != 0) << (c * 4);
        bits |= (u32)(v.y != 0) << (c * 4 + 1);
        bits |= (u32)(v.z != 0) << (c * 4 + 2);
        bits |= (u32)(v.w != 0) << (c * 4 + 3);
      }
      amaskb[gtid] = bits;
    }
    return;
  }

  const int wave = tid >> 6, lane = tid & 63;
  const int lr = lane & 15, lq = lane >> 4;
  const int row0 = blockIdx.x * 128;
  const int col0 = blockIdx.y * 128;
  const int wm = (wave & 1) * 64, wn = (wave >> 1) * 64;

  floatx4 acc[4][4];
#pragma unroll
  for (int i = 0; i < 4; i++)
#pragma unroll
    for (int j = 0; j < 4; j++) acc[i][j] = (floatx4){0.f, 0.f, 0.f, 0.f};

  const float* A = (z == 0) ? key : (z == 1) ? value : query;
  const u16* Wb  = (z == 0) ? Wkb : (z == 1) ? Wvb : Wqb;

  const int cc0 = tid, cc1 = 256 + tid;
  const u16* Wg0 = Wb + (size_t)(col0 + (cc0 >> 2)) * 1024 + (cc0 & 3) * 8;
  const u16* Wg1 = Wb + (size_t)(col0 + (cc1 >> 2)) * 1024 + (cc1 & 3) * 8;

  auto stageW = [&](int t, int wbuf) {
    const int o = t * 32;
    async16(Wg0 + o, &Ws[wbuf][wave * 512]);
    async16(Wg1 + o, &Ws[wbuf][2048 + wave * 512]);
  };
  auto loadA = [&](int t, float4* ag) {
#pragma unroll
    for (int it = 0; it < 4; it++) {
      const int cc = it * 256 + tid;
      ag[it] = *(const float4*)(A + (size_t)(row0 + (cc >> 3)) * 1024 +
                                (cc & 7) * 4 + t * 32);
    }
  };
  auto writeA = [&](int abuf, const float4* ag) {
#pragma unroll
    for (int it = 0; it < 4; it++) {
      const int cc = it * 256 + tid;
      short4v s;
      s[0] = (short)f2b(ag[it].x); s[1] = (short)f2b(ag[it].y);
      s[2] = (short)f2b(ag[it].z); s[3] = (short)f2b(ag[it].w);
      *(short4v*)(&As[abuf][(cc >> 3) * 32 + (cc & 7) * 4]) = s;
    }
  };

  float4 ag[3][4];

  // Prologue. Ledger after each line in comments (oldest -> newest).
  stageW(0, 0);                                        // [W0:2]
  stageW(1, 1);                                        // [W0,W1] = 4
  loadA(0, ag[0]);                                     // [W0,W1,A0] = 8
  loadA(1, ag[1]);                                     // [..,A1] = 12
  asm volatile("s_waitcnt vmcnt(4)" ::: "memory");     // retire W0,W1,A0 -> [A1]
  writeA(0, ag[0]);
  loadA(2, ag[2]);                                     // [A1,A2] = 8

#pragma unroll
  for (int t = 0; t < 32; t++) {
    const int abuf = t & 1;
    // T1: retire W(t) (per-wave, BEFORE barrier -> cross-wave LDS visibility)
    asm volatile("s_waitcnt vmcnt(10)" ::: "memory");
    // T2: my ds_writes of As[abuf] (from t-1) complete before barrier
    asm volatile("s_waitcnt lgkmcnt(0)" ::: "memory");
    __builtin_amdgcn_s_barrier();
    asm volatile("" ::: "memory");  // no memory-op hoisting above the barrier

    const int t2 = (t + 2 < 32) ? t + 2 : 31;
    const int t3 = (t + 3 < 32) ? t + 3 : 31;
    stageW(t2, (t + 2) % 3);        // +2
    loadA(t3, ag[t % 3]);           // +4

    short8 af[4], wf[4];
#pragma unroll
    for (int mi = 0; mi < 4; mi++)
      af[mi] = *(const short8*)(&As[abuf][(wm + mi * 16 + lr) * 32 + lq * 8]);
#pragma unroll
    for (int ni = 0; ni < 4; ni++)
      wf[ni] = *(const short8*)(&Ws[t % 3][(wn + ni * 16 + lr) * 32 + lq * 8]);
#pragma unroll
    for (int mi = 0; mi < 4; mi++)
#pragma unroll
      for (int ni = 0; ni < 4; ni++)
        acc[mi][ni] = __builtin_amdgcn_mfma_f32_16x16x32_bf16(af[mi], wf[ni],
                                                              acc[mi][ni], 0, 0, 0);

    // T7: retire A(t+1) (private regs; matches compiler's own auto-wait)
    if (t == 0) asm volatile("s_waitcnt vmcnt(10)" ::: "memory");
    else        asm volatile("s_waitcnt vmcnt(12)" ::: "memory");
    writeA(abuf ^ 1, ag[(t + 1) % 3]);
  }

  const float scale = (z == 2) ? QSCALE : 1.0f;
  const float* bias = (z == 0) ? bk : (z == 1) ? bv : bq;
  u16* outb = (z == 0) ? kbuf : qbuf;

#pragma unroll
  for (int ni = 0; ni < 4; ni++) {
    const int col = col0 + wn + ni * 16 + lr;
    const float bvv = bias[col];
#pragma unroll
    for (int mi = 0; mi < 4; mi++) {
#pragma unroll
      for (int r = 0; r < 4; r++) {
        const int row = row0 + wm + mi * 16 + lq * 4 + r;
        const float v = (acc[mi][ni][r] + bvv) * scale;
        const int b = row >> 10, l = row & 1023, h = col >> 6, dh = col & 63;
        if (z == 1)
          vbt[((b * HH + h) * DHH + dh) * LL + l] = f2b(v);   // (B,H,DH,L)
        else
          outb[((b * HH + h) * LL + l) * DHH + dh] = f2b(v);  // (B,H,L,DH)
      }
    }
  }
}

// bf16 GEMM (O-projection), R6 deep-issue (unchanged, proven).
template <int OUT>
__global__ __launch_bounds__(256) void gemm_b(
    const u16* __restrict__ A, const u16* __restrict__ Wb,
    const float* __restrict__ bias, void* __restrict__ outv, float scale) {
  __shared__ u16 As[3][128 * 32];
  __shared__ u16 Ws[3][128 * 32];

  const int tid = threadIdx.x;
  const int wave = tid >> 6, lane = tid & 63;
  const int lr = lane & 15, lq = lane >> 4;
  const int row0 = blockIdx.x * 128;
  const int col0 = blockIdx.y * 128;
  const int wm = (wave & 1) * 64, wn = (wave >> 1) * 64;

  floatx4 acc[4][4];
#pragma unroll
  for (int i = 0; i < 4; i++)
#pragma unroll
    for (int j = 0; j < 4; j++) acc[i][j] = (floatx4){0.f, 0.f, 0.f, 0.f};

  const int cc0 = tid, cc1 = 256 + tid;
  const u16* Ag0 = A + (size_t)(row0 + (cc0 >> 2)) * 1024 + (cc0 & 3) * 8;
  const u16* Ag1 = A + (size_t)(row0 + (cc1 >> 2)) * 1024 + (cc1 & 3) * 8;
  const u16* Wg0 = Wb + (size_t)(col0 + (cc0 >> 2)) * 1024 + (cc0 & 3) * 8;
  const u16* Wg1 = Wb + (size_t)(col0 + (cc1 >> 2)) * 1024 + (cc1 & 3) * 8;

  auto stage = [&](int t, int buf) {
    const int o = t * 32;
    async16(Ag0 + o, &As[buf][wave * 512]);
    async16(Ag1 + o, &As[buf][2048 + wave * 512]);
    async16(Wg0 + o, &Ws[buf][wave * 512]);
    async16(Wg1 + o, &Ws[buf][2048 + wave * 512]);
  };

  stage(0, 0);   // [S0:4]
  stage(1, 1);   // [S0,S1] = 8

#pragma unroll
  for (int t = 0; t < 32; t++) {
    // retire S(t) per-wave BEFORE the barrier -> tile t LDS-resident for all
    asm volatile("s_waitcnt vmcnt(4)" ::: "memory");
    __builtin_amdgcn_s_barrier();
    asm volatile("" ::: "memory");

    const int t2 = (t + 2 < 32) ? t + 2 : 31;
    stage(t2, (t + 2) % 3);

    short8 af[4], wf[4];
#pragma unroll
    for (int mi = 0; mi < 4; mi++)
      af[mi] = *(const short8*)(&As[t % 3][(wm + mi * 16 + lr) * 32 + lq * 8]);
#pragma unroll
    for (int ni = 0; ni < 4; ni++)
      wf[ni] = *(const short8*)(&Ws[t % 3][(wn + ni * 16 + lr) * 32 + lq * 8]);
#pragma unroll
    for (int mi = 0; mi < 4; mi++)
#pragma unroll
      for (int ni = 0; ni < 4; ni++)
        acc[mi][ni] = __builtin_amdgcn_mfma_f32_16x16x32_bf16(af[mi], wf[ni],
                                                              acc[mi][ni], 0, 0, 0);
  }

#pragma unroll
  for (int ni = 0; ni < 4; ni++) {
    const int col = col0 + wn + ni * 16 + lr;
    const float bv = bias[col];
#pragma unroll
    for (int mi = 0; mi < 4; mi++) {
#pragma unroll
      for (int r = 0; r < 4; r++) {
        const int row = row0 + wm + mi * 16 + lq * 4 + r;
        const float v = (acc[mi][ni][r] + bv) * scale;
        if (OUT == 0) {
          const int b = row >> 10, l = row & 1023, h = col >> 6, dh = col & 63;
          ((u16*)outv)[((b * HH + h) * LL + l) * DHH + dh] = f2b(v);
        } else if (OUT == 2) {
          const int b = row >> 10, l = row & 1023, h = col >> 6, dh = col & 63;
          ((u16*)outv)[((b * HH + h) * DHH + dh) * LL + l] = f2b(v);
        } else {
          ((float*)outv)[(size_t)row * 1024 + col] = v;
        }
      }
    }
  }
}

// Flash attention (R7-proven body) + folded top blocks (id >= 1024):
// short top blocks fill attn's tail rounds; one launch + gap removed.
__global__ __launch_bounds__(256) void attn_fast(
    const u16* __restrict__ qbuf, const u16* __restrict__ kbuf,
    const u16* __restrict__ vbt, const u32* __restrict__ maskb,
    const u32* __restrict__ amaskb, u16* __restrict__ ctx,
    float* __restrict__ top) {
  __shared__ u16 Ks[2][64 * 64];
  __shared__ u16 Vts[2][64 * 64];   // [dh][key], granule-swizzled

  const int id = blockIdx.x;
  const int tid = threadIdx.x, wave = tid >> 6, lane = tid & 63;
  const int lr = lane & 15, lq = lane >> 4;
  const int lq4 = lq * 4;
  const int x7 = lr & 7;
  const int cs0 = ((0 + lq) ^ x7) * 8;
  const int cs1 = ((4 + lq) ^ x7) * 8;

  if (id >= 1024) {
    // ---- top path: top[b] = (K0 . Q0^T) * ln2 (R7 top_kernel body) ----
    const int id2 = id - 1024;
    const int kt = id2 & 7, qt = (id2 >> 3) & 7, b = id2 >> 6;
    u16* Qs = &Ks[0][0];    // 16 KB
    u16* Kts = &Vts[0][0];  // 16 KB

    const u16* Qg = qbuf + (size_t)((b * HH + 0) * LL + qt * 128) * DHH;
    const u16* Kg = kbuf + (size_t)((b * HH + 0) * LL + kt * 128) * DHH;

#pragma unroll
    for (int rnd = 0; rnd < 4; rnd++) {
      const int g = rnd * 256 + tid;
      const int row = g >> 3, col = (g & 7) ^ (row & 7);
      async16(Qg + row * 64 + col * 8, Qs + (rnd * 256 + wave * 64) * 8);
      async16(Kg + row * 64 + col * 8, Kts + (rnd * 256 + wave * 64) * 8);
    }
    __syncthreads();

    short8 qf[2][2];
#pragma unroll
    for (int mi = 0; mi < 2; mi++) {
      qf[mi][0] = *(const short8*)(Qs + (wave * 32 + mi * 16 + lr) * 64 + cs0);
      qf[mi][1] = *(const short8*)(Qs + (wave * 32 + mi * 16 + lr) * 64 + cs1);
    }

#pragma unroll
    for (int nj = 0; nj < 8; nj++) {
      const short8 kf0 = *(const short8*)(Kts + (nj * 16 + lr) * 64 + cs0);
      const short8 kf1 = *(const short8*)(Kts + (nj * 16 + lr) * 64 + cs1);
#pragma unroll
      for (int mi = 0; mi < 2; mi++) {
        floatx4 z = (floatx4){0.f, 0.f, 0.f, 0.f};
        z = __builtin_amdgcn_mfma_f32_16x16x32_bf16(kf1, qf[mi][1], z, 0, 0, 0);
        z = __builtin_amdgcn_mfma_f32_16x16x32_bf16(kf0, qf[mi][0], z, 0, 0, 0);
        const int row = qt * 128 + wave * 32 + mi * 16 + lr;
        float4 t;
        t.x = z[0] * LN2F; t.y = z[1] * LN2F;
        t.z = z[2] * LN2F; t.w = z[3] * LN2F;
        *(float4*)(top + (size_t)(b * LL + row) * LL + kt * 128 + nj * 16 + lq4) = t;
      }
    }
    return;
  }

  // ---- attention path (R7-proven, unchanged) ----
  const int xcd = id & 7;
  const int r_ = id >> 3;
  const int b = r_ & 7;
  const int h = (((r_ >> 3) & 1) << 3) | (xcd ^ b);
  const int qt = r_ >> 4;

  const u16* Qg = qbuf + (size_t)((b * HH + h) * LL + qt * 128) * DHH;
  const u16* Kg = kbuf + (size_t)((b * HH + h) * LL) * DHH;
  const u16* Vtg = vbt + (size_t)((b * HH + h) * DHH) * LL;  // [dh][l]

  short8 qf[2][2];
#pragma unroll
  for (int mi = 0; mi < 2; mi++)
#pragma unroll
    for (int kk = 0; kk < 2; kk++)
      qf[mi][kk] = *(const short8*)(Qg + (wave * 32 + mi * 16 + lr) * 64 +
                                    kk * 32 + lq * 8);

  const int g0 = tid, g1 = 256 + tid;
  const int kr0 = g0 >> 3, kc0 = (g0 & 7) ^ (kr0 & 7);
  const int kr1 = g1 >> 3, kc1 = (g1 & 7) ^ (kr1 & 7);
  const int lqh = lq >> 1, lqb = (lq & 1) * 4;
  const int go00 = ((0 + lqh) ^ x7) * 8 + lqb;  // kk=0 lo
  const int go01 = ((2 + lqh) ^ x7) * 8 + lqb;  // kk=0 hi
  const int go10 = ((4 + lqh) ^ x7) * 8 + lqb;  // kk=1 lo
  const int go11 = ((6 + lqh) ^ x7) * 8 + lqb;  // kk=1 hi

  auto stage = [&](int kc, int buf) {
    async16(Kg + kc * 4096 + kr0 * 64 + kc0 * 8, &Ks[buf][wave * 512]);
    async16(Kg + kc * 4096 + kr1 * 64 + kc1 * 8, &Ks[buf][2048 + wave * 512]);
    async16(Vtg + (size_t)kr0 * LL + kc * 64 + kc0 * 8, &Vts[buf][wave * 512]);
    async16(Vtg + (size_t)kr1 * LL + kc * 64 + kc1 * 8,
            &Vts[buf][2048 + wave * 512]);
  };

  const int rowm0 = qt * 128 + wave * 32 + lr;         // mi=0 row
  const int rowm1 = rowm0 + 16;                        // mi=1 row
  const u32* mb0 = (h < 8) ? maskb + (size_t)(b * LL + rowm0) * 32
                           : amaskb + b * 32;
  const u32* mb1 = (h < 8) ? maskb + (size_t)(b * LL + rowm1) * 32
                           : amaskb + b * 32;
  uint2 mwc0 = *(const uint2*)(mb0);
  uint2 mwc1 = *(const uint2*)(mb1);

  float mrow[2], lrow[2];
  floatx4 Oacc[2][4];
#pragma unroll
  for (int mi = 0; mi < 2; mi++) {
    mrow[mi] = NEGBIG;
    lrow[mi] = 0.f;
#pragma unroll
    for (int ni = 0; ni < 4; ni++) Oacc[mi][ni] = (floatx4){0.f, 0.f, 0.f, 0.f};
  }

  stage(0, 0);

  for (int kc = 0; kc < 16; kc++) {
    const int cur = kc & 1;
    __syncthreads();
    uint2 mwn0, mwn1;
    if (kc < 15) {
      stage(kc + 1, cur ^ 1);
      mwn0 = *(const uint2*)(mb0 + (kc + 1) * 2);   // in flight during compute
      mwn1 = *(const uint2*)(mb1 + (kc + 1) * 2);
    }
    const u16* Ksc = Ks[cur];
    const u16* Vtsc = Vts[cur];

    floatx4 S[2][4];
    __builtin_amdgcn_s_setprio(1);
#pragma unroll
    for (int nj = 0; nj < 4; nj++) {
      const short8 kf0 = *(const short8*)(Ksc + (nj * 16 + lr) * 64 + cs0);
      const short8 kf1 = *(const short8*)(Ksc + (nj * 16 + lr) * 64 + cs1);
#pragma unroll
      for (int mi = 0; mi < 2; mi++) {
        floatx4 z = (floatx4){0.f, 0.f, 0.f, 0.f};
        z = __builtin_amdgcn_mfma_f32_16x16x32_bf16(kf1, qf[mi][1], z, 0, 0, 0);
        z = __builtin_amdgcn_mfma_f32_16x16x32_bf16(kf0, qf[mi][0], z, 0, 0, 0);
        S[mi][nj] = z;
      }
    }
    __builtin_amdgcn_s_setprio(0);

    short8 pf[2][2];
#pragma unroll
    for (int mi = 0; mi < 2; mi++) {
      {
        const uint2 mw = mi ? mwc1 : mwc0;
#pragma unroll
        for (int nj = 0; nj < 4; nj++) {
          const u32 nib = (((nj & 2) ? mw.y : mw.x) >> ((nj & 1) * 16 + lq4)) & 15u;
#pragma unroll
          for (int r = 0; r < 4; r++)
            if ((nib >> r) & 1) S[mi][nj][r] = -1e18f;
        }
      }

      // online softmax (exp2 domain) with defer-max (T13)
      float cm = fmaxf(fmaxf(S[mi][0][0], S[mi][0][1]),
                       fmaxf(S[mi][0][2], S[mi][0][3]));
#pragma unroll
      for (int nj = 1; nj < 4; nj++)
        cm = fmaxf(cm, fmaxf(fmaxf(S[mi][nj][0], S[mi][nj][1]),
                             fmaxf(S[mi][nj][2], S[mi][nj][3])));
      cm = fmaxf(cm, __shfl_xor(cm, 16, 64));
      cm = fmaxf(cm, __shfl_xor(cm, 32, 64));
      const float mold = mrow[mi];
      if (!__all(cm <= mold + DEFER_THR)) {
        const float mnew = fmaxf(mold, cm);
        const float alpha = fexp2(mold - mnew);
        mrow[mi] = mnew;
        lrow[mi] *= alpha;
#pragma unroll
        for (int ni = 0; ni < 4; ni++)
#pragma unroll
          for (int r = 0; r < 4; r++) Oacc[mi][ni][r] *= alpha;
      }
      const float mcur = mrow[mi];
      float rs = 0.f;
#pragma unroll
      for (int nj = 0; nj < 4; nj++)
#pragma unroll
        for (int r = 0; r < 4; r++) {
          const float p = fexp2(S[mi][nj][r] - mcur);
          S[mi][nj][r] = p;
          rs += p;
        }
      rs += __shfl_xor(rs, 16, 64);
      rs += __shfl_xor(rs, 32, 64);
      lrow[mi] += rs;

      // P fragment under key-relabeling kappa (R2-proven)
#pragma unroll
      for (int kk = 0; kk < 2; kk++) {
        short8 p;
#pragma unroll
        for (int r = 0; r < 4; r++) {
          p[r] = (short)f2b(S[mi][2 * kk][r]);
          p[4 + r] = (short)f2b(S[mi][2 * kk + 1][r]);
        }
        pf[mi][kk] = p;
      }
    }

    __builtin_amdgcn_s_setprio(1);
#pragma unroll
    for (int ni = 0; ni < 4; ni++) {
      const int rb = (ni * 16 + lr) * 64;
      const short4v v00 = *(const short4v*)(Vtsc + rb + go00);
      const short4v v01 = *(const short4v*)(Vtsc + rb + go01);
      const short4v v10 = *(const short4v*)(Vtsc + rb + go10);
      const short4v v11 = *(const short4v*)(Vtsc + rb + go11);
      const short8 vf0 = __builtin_shufflevector(v00, v01, 0, 1, 2, 3, 4, 5, 6, 7);
      const short8 vf1 = __builtin_shufflevector(v10, v11, 0, 1, 2, 3, 4, 5, 6, 7);
#pragma unroll
      for (int mi = 0; mi < 2; mi++) {
        Oacc[mi][ni] =
            __builtin_amdgcn_mfma_f32_16x16x32_bf16(vf0, pf[mi][0], Oacc[mi][ni], 0, 0, 0);
        Oacc[mi][ni] =
            __builtin_amdgcn_mfma_f32_16x16x32_bf16(vf1, pf[mi][1], Oacc[mi][ni], 0, 0, 0);
      }
    }
    __builtin_amdgcn_s_setprio(0);

    if (kc < 15) { mwc0 = mwn0; mwc1 = mwn1; }
  }

#pragma unroll
  for (int mi = 0; mi < 2; mi++) {
    const float inv = 1.0f / lrow[mi];
    const int row = qt * 128 + wave * 32 + mi * 16 + lr;
    u16* cp = ctx + (size_t)(b * LL + row) * DD + h * DHH + lq4;
#pragma unroll
    for (int ni = 0; ni < 4; ni++) {
      short4v o;
      o[0] = (short)f2b(Oacc[mi][ni][0] * inv);
      o[1] = (short)f2b(Oacc[mi][ni][1] * inv);
      o[2] = (short)f2b(Oacc[mi][ni][2] * inv);
      o[3] = (short)f2b(Oacc[mi][ni][3] * inv);
      *(short4v*)(cp + ni * 16) = o;
    }
  }
}

// ===========================================================================
// FALLBACK PATH (R5-proven, 64 MB ws)
// ===========================================================================
template <int MODE>
__global__ __launch_bounds__(256) void gemm_k(
    const void* __restrict__ Av, const float* __restrict__ W,
    const float* __restrict__ biasp, void* __restrict__ outv, float scale) {
  __shared__ u16 As[128 * 32];
  __shared__ u16 Ws[128 * 32];
  const int tid = threadIdx.x;
  const int wave = tid >> 6, lane = tid & 63;
  const int lr = lane & 15, lq = lane >> 4;
  const int row0 = blockIdx.x * 128;
  const int col0 = blockIdx.y * 128;
  const int wm = (wave & 1) * 64, wn = (wave >> 1) * 64;
  floatx4 acc[4][4];
#pragma unroll
  for (int i = 0; i < 4; i++)
#pragma unroll
    for (int j = 0; j < 4; j++) acc[i][j] = (floatx4){0.f, 0.f, 0.f, 0.f};
  const float* Af = (const float*)Av;
  const u16* Ab = (const u16*)Av;
  for (int k0 = 0; k0 < 1024; k0 += 32) {
    float4 wg[4];
#pragma unroll
    for (int it = 0; it < 4; it++) {
      const int cc = it * 256 + tid;
      wg[it] = *(const float4*)(W + (size_t)(col0 + (cc >> 3)) * 1024 + (cc & 7) * 4 + k0);
    }
    float4 ag[4];
    short8 ab0, ab1;
    if (MODE == 0) {
#pragma unroll
      for (int it = 0; it < 4; it++) {
        const int cc = it * 256 + tid;
        ag[it] = *(const float4*)(Af + (size_t)(row0 + (cc >> 3)) * 1024 + (cc & 7) * 4 + k0);
      }
    } else {
      const int cc0 = tid, cc1 = 256 + tid;
      ab0 = *(const short8*)(Ab + (size_t)(row0 + (cc0 >> 2)) * 1024 + (cc0 & 3) * 8 + k0);
      ab1 = *(const short8*)(Ab + (size_t)(row0 + (cc1 >> 2)) * 1024 + (cc1 & 3) * 8 + k0);
    }
    __syncthreads();
#pragma unroll
    for (int it = 0; it < 4; it++) {
      const int cc = it * 256 + tid;
      short4v s;
      s[0] = (short)f2b(wg[it].x); s[1] = (short)f2b(wg[it].y);
      s[2] = (short)f2b(wg[it].z); s[3] = (short)f2b(wg[it].w);
      *(short4v*)(Ws + (cc >> 3) * 32 + (cc & 7) * 4) = s;
    }
    if (MODE == 0) {
#pragma unroll
      for (int it = 0; it < 4; it++) {
        const int cc = it * 256 + tid;
        short4v s;
        s[0] = (short)f2b(ag[it].x); s[1] = (short)f2b(ag[it].y);
        s[2] = (short)f2b(ag[it].z); s[3] = (short)f2b(ag[it].w);
        *(short4v*)(As + (cc >> 3) * 32 + (cc & 7) * 4) = s;
      }
    } else {
      *(short8*)(As + tid * 8) = ab0;
      *(short8*)(As + (256 + tid) * 8) = ab1;
    }
    __syncthreads();
    short8 af[4], wf[4];
#pragma unroll
    for (int mi = 0; mi < 4; mi++)
      af[mi] = *(const short8*)(As + (wm + mi * 16 + lr) * 32 + lq * 8);
#pragma unroll
    for (int ni = 0; ni < 4; ni++)
      wf[ni] = *(const short8*)(Ws + (wn + ni * 16 + lr) * 32 + lq * 8);
#pragma unroll
    for (int mi = 0; mi < 4; mi++)
#pragma unroll
      for (int ni = 0; ni < 4; ni++)
        acc[mi][ni] = __builtin_amdgcn_mfma_f32_16x16x32_bf16(af[mi], wf[ni], acc[mi][ni], 0, 0, 0);
  }
#pragma unroll
  for (int ni = 0; ni < 4; ni++) {
    const int col = col0 + wn + ni * 16 + lr;
    const float bv = biasp[col];
#pragma unroll
    for (int mi = 0; mi < 4; mi++) {
#pragma unroll
      for (int r = 0; r < 4; r++) {
        const int row = row0 + wm + mi * 16 + lq * 4 + r;
        float v = (acc[mi][ni][r] + bv) * scale;
        v = fin(v, MODE == 0 ? 700.0f : 1000.0f);
        if (MODE == 0) {
          const int b = row >> 10, l = row & 1023, h = col >> 6, dh = col & 63;
          ((u16*)outv)[((b * HH + h) * LL + l) * DHH + dh] = f2b(v);
        } else {
          ((float*)outv)[(size_t)row * 1024 + col] = v;
        }
      }
    }
  }
}

__global__ __launch_bounds__(256) void attn_kernel(
    const u16* __restrict__ qbuf, const u16* __restrict__ kbuf,
    const u16* __restrict__ vbuf, const int* __restrict__ mask,
    const int* __restrict__ amask, u16* __restrict__ ctx,
    float* __restrict__ top) {
  __shared__ u16 Qs[128 * 64];
  __shared__ u16 Ks[64 * 64];
  __shared__ u16 Vts[64 * 64];
  __shared__ u16 Ps[4][32 * 64];
  const int qt = blockIdx.x, h = blockIdx.y, b = blockIdx.z;
  const int tid = threadIdx.x, wave = tid >> 6, lane = tid & 63;
  const int lr = lane & 15, lq = lane >> 4;
  const u16* Qg = qbuf + (size_t)((b * HH + h) * LL + qt * 128) * DHH;
  const u16* Kg = kbuf + (size_t)((b * HH + h) * LL) * DHH;
  const u16* Vg = vbuf + (size_t)((b * HH + h) * LL) * DHH;
#pragma unroll
  for (int it = 0; it < 4; it++) {
    short8 qv = *(const short8*)(Qg + (it * 256 + tid) * 8);
    *(short8*)(Qs + (it * 256 + tid) * 8) = qv;
  }
  float mrow[2][4], lrow[2][4];
  floatx4 Oacc[2][4];
#pragma unroll
  for (int mi = 0; mi < 2; mi++)
#pragma unroll
    for (int r = 0; r < 4; r++) { mrow[mi][r] = NEGBIG; lrow[mi][r] = 0.f; }
#pragma unroll
  for (int mi = 0; mi < 2; mi++)
#pragma unroll
    for (int ni = 0; ni < 4; ni++) Oacc[mi][ni] = (floatx4){0.f, 0.f, 0.f, 0.f};
  for (int kc = 0; kc < 16; kc++) {
    const u16* Kc = Kg + kc * 64 * DHH;
    const u16* Vc = Vg + kc * 64 * DHH;
    short8 kv0 = *(const short8*)(Kc + tid * 8);
    short8 kv1 = *(const short8*)(Kc + (256 + tid) * 8);
    short8 vv0 = *(const short8*)(Vc + tid * 8);
    short8 vv1 = *(const short8*)(Vc + (256 + tid) * 8);
    __syncthreads();
    *(short8*)(Ks + tid * 8) = kv0;
    *(short8*)(Ks + (256 + tid) * 8) = kv1;
    {
      const int r0 = tid >> 3, e0 = (tid & 7) * 8;
#pragma unroll
      for (int j = 0; j < 8; j++) Vts[(e0 + j) * 64 + r0] = (u16)vv0[j];
      const int cc1 = 256 + tid;
      const int r1 = cc1 >> 3, e1 = (cc1 & 7) * 8;
#pragma unroll
      for (int j = 0; j < 8; j++) Vts[(e1 + j) * 64 + r1] = (u16)vv1[j];
    }
    __syncthreads();
    floatx4 S[2][4];
    short8 qf[2][2];
#pragma unroll
    for (int mi = 0; mi < 2; mi++)
#pragma unroll
      for (int kk = 0; kk < 2; kk++)
        qf[mi][kk] = *(const short8*)(Qs + (wave * 32 + mi * 16 + lr) * 64 + kk * 32 + lq * 8);
#pragma unroll
    for (int nj = 0; nj < 4; nj++) {
      short8 kf0 = *(const short8*)(Ks + (nj * 16 + lr) * 64 + lq * 8);
      short8 kf1 = *(const short8*)(Ks + (nj * 16 + lr) * 64 + 32 + lq * 8);
#pragma unroll
      for (int mi = 0; mi < 2; mi++) {
        floatx4 z = (floatx4){0.f, 0.f, 0.f, 0.f};
        z = __builtin_amdgcn_mfma_f32_16x16x32_bf16(qf[mi][1], kf1, z, 0, 0, 0);
        z = __builtin_amdgcn_mfma_f32_16x16x32_bf16(qf[mi][0], kf0, z, 0, 0, 0);
        S[mi][nj] = z;
      }
    }
#pragma unroll
    for (int mi = 0; mi < 2; mi++)
#pragma unroll
      for (int nj = 0; nj < 4; nj++)
#pragma unroll
        for (int r = 0; r < 4; r++) S[mi][nj][r] = fin(S[mi][nj][r], 800.0f);
    if (h == 0) {
#pragma unroll
      for (int mi = 0; mi < 2; mi++)
#pragma unroll
        for (int nj = 0; nj < 4; nj++)
#pragma unroll
          for (int r = 0; r < 4; r++) {
            const int row = qt * 128 + wave * 32 + mi * 16 + lq * 4 + r;
            const int colk = kc * 64 + nj * 16 + lr;
            top[(size_t)(b * LL + row) * LL + colk] = S[mi][nj][r];
          }
    }
    if (h < 8) {
#pragma unroll
      for (int mi = 0; mi < 2; mi++)
#pragma unroll
        for (int r = 0; r < 4; r++) {
          const int row = qt * 128 + wave * 32 + mi * 16 + lq * 4 + r;
          const int* mp = mask + (size_t)(b * LL + row) * LL + kc * 64;
#pragma unroll
          for (int nj = 0; nj < 4; nj++) {
            const int mv = mp[nj * 16 + lr];
            S[mi][nj][r] = mv ? -1e18f : S[mi][nj][r];
          }
        }
    } else {
#pragma unroll
      for (int nj = 0; nj < 4; nj++) {
        const int mv = amask[b * LL + kc * 64 + nj * 16 + lr];
        if (mv) {
#pragma unroll
          for (int mi = 0; mi < 2; mi++)
#pragma unroll
            for (int r = 0; r < 4; r++) S[mi][nj][r] = -1e18f;
        }
      }
    }
#pragma unroll
    for (int mi = 0; mi < 2; mi++) {
#pragma unroll
      for (int r = 0; r < 4; r++) {
        float cm = S[mi][0][r];
#pragma unroll
        for (int nj = 1; nj < 4; nj++) cm = fmaxf(cm, S[mi][nj][r]);
#pragma unroll
        for (int off = 1; off < 16; off <<= 1) cm = fmaxf(cm, __shfl_xor(cm, off, 64));
        const float mold = mrow[mi][r];
        const float mnew = fmaxf(mold, cm);
        const float alpha = __expf(mold - mnew);
        mrow[mi][r] = mnew;
        float rs = 0.f;
#pragma unroll
        for (int nj = 0; nj < 4; nj++) {
          const float p = __expf(S[mi][nj][r] - mnew);
          S[mi][nj][r] = p;
          rs += p;
        }
#pragma unroll
        for (int off = 1; off < 16; off <<= 1) rs += __shfl_xor(rs, off, 64);
        lrow[mi][r] = lrow[mi][r] * alpha + rs;
#pragma unroll
        for (int ni = 0; ni < 4; ni++) Oacc[mi][ni][r] *= alpha;
      }
    }
#pragma unroll
    for (int mi = 0; mi < 2; mi++)
#pragma unroll
      for (int nj = 0; nj < 4; nj++)
#pragma unroll
        for (int r = 0; r < 4; r++)
          Ps[wave][(mi * 16 + lq * 4 + r) * 64 + nj * 16 + lr] = f2b(S[mi][nj][r]);
    __syncthreads();
#pragma unroll
    for (int kk = 0; kk < 2; kk++) {
      short8 pf[2];
#pragma unroll
      for (int mi = 0; mi < 2; mi++)
        pf[mi] = *(const short8*)(&Ps[wave][(mi * 16 + lr) * 64 + kk * 32 + lq * 8]);
#pragma unroll
      for (int ni = 0; ni < 4; ni++) {
        short8 vf = *(const short8*)(Vts + (ni * 16 + lr) * 64 + kk * 32 + lq * 8);
#pragma unroll
        for (int mi = 0; mi < 2; mi++)
          Oacc[mi][ni] = __builtin_amdgcn_mfma_f32_16x16x32_bf16(pf[mi], vf, Oacc[mi][ni], 0, 0, 0);
      }
    }
  }
#pragma unroll
  for (int mi = 0; mi < 2; mi++)
#pragma unroll
    for (int r = 0; r < 4; r++) {
      const float inv = 1.0f / lrow[mi][r];
      const int row = qt * 128 + wave * 32 + mi * 16 + lq * 4 + r;
#pragma unroll
      for (int ni = 0; ni < 4; ni++) {
        const int col = h * DHH + ni * 16 + lr;
        ctx[(size_t)(b * LL + row) * DD + col] = f2b(fin(Oacc[mi][ni][r] * inv, 900.0f));
      }
    }
}

// ===========================================================================
extern "C" void kernel_launch(void* const* d_in, const int* in_sizes, int n_in,
                              void* d_out, int out_size, void* d_ws, size_t ws_size,
                              hipStream_t stream) {
  const float* key   = (const float*)d_in[0];
  const float* value = (const float*)d_in[1];
  const float* query = (const float*)d_in[2];
  const int* mask    = (const int*)d_in[3];
  const int* amask   = (const int*)d_in[4];
  const float* Wk = (const float*)d_in[5];
  const float* bk = (const float*)d_in[6];
  const float* Wv = (const float*)d_in[7];
  const float* bv = (const float*)d_in[8];
  const float* Wq = (const float*)d_in[9];
  const float* bq = (const float*)d_in[10];
  const float* Wo = (const float*)d_in[11];
  const float* bo = (const float*)d_in[12];

  float* outp = (float*)d_out;                  // out (B,L,D) f32
  float* topp = outp + (size_t)BB * LL * DD;    // top_score (B,L,L) f32

  const size_t M8 = (size_t)BB * LL * DD;       // 8M elems
  const size_t M1 = (size_t)DD * DD;            // 1M elems
  const size_t NEED = (size_t)90 * 1024 * 1024; // fast-path ws bytes

  dim3 tb(256), gg(64, 8, 1), ga(8, 16, 8);

  if (ws_size >= NEED) {
    u16* W16 = (u16*)d_ws;
    u16* Wkb = W16;                              // 4 weight buffers (bf16)
    u16* Wvb = Wkb + M1;
    u16* Wqb = Wvb + M1;
    u16* Wob = Wqb + M1;
    u32* maskb = (u32*)(Wob + M1);               // 1 MB (+1 KB) in slots 4-5
    u32* amaskb = maskb + 262144;
    u16* kbuf = W16 + 6 * M1;                    // 16 MB each
    u16* vbt  = kbuf + M8;
    u16* qbuf = vbt + M8;
    u16* cbuf = qbuf + M8;

    convpack_w<<<dim3(32, 4), tb, 0, stream>>>(
        Wk, Wv, Wq, Wo, Wkb, Wvb, Wqb, Wob);
    gemm_qkv<<<dim3(64, 8, 4), tb, 0, stream>>>(
        key, value, query, Wkb, Wvb, Wqb, bk, bv, bq, mask, amask,
        kbuf, vbt, qbuf, maskb, amaskb);
    attn_fast<<<dim3(1536, 1, 1), tb, 0, stream>>>(qbuf, kbuf, vbt, maskb,
                                                   amaskb, cbuf, topp);
    gemm_b<1><<<gg, tb, 0, stream>>>(cbuf, Wob, bo, outp, 1.0f);
  } else {
    u16* kbuf = (u16*)d_ws;
    u16* vbuf = kbuf + M8;
    u16* qbuf = vbuf + M8;
    u16* cbuf = qbuf + M8;
    gemm_k<0><<<gg, tb, 0, stream>>>(key,   Wk, bk, kbuf, 1.0f);
    gemm_k<0><<<gg, tb, 0, stream>>>(value, Wv, bv, vbuf, 1.0f);
    gemm_k<0><<<gg, tb, 0, stream>>>(query, Wq, bq, qbuf, 0.125f);
    attn_kernel<<<ga, tb, 0, stream>>>(qbuf, kbuf, vbuf, mask, amask, cbuf, topp);
    gemm_k<1><<<gg, tb, 0, stream>>>(cbuf, Wo, bo, outp, 1.0f);
  }
}

// Round 10
// 374.553 us; speedup vs baseline: 1.1076x; 1.0896x over previous
//
#include <hip/hip_runtime.h>
#include <hip/hip_bf16.h>

typedef unsigned short u16;
typedef unsigned int u32;
typedef __attribute__((ext_vector_type(8))) short short8;   // 8 bf16 MFMA frag
typedef __attribute__((ext_vector_type(4))) short short4v;  // 4 bf16
typedef __attribute__((ext_vector_type(4))) float floatx4;  // MFMA C/D frag

#define BB 8
#define LL 1024
#define DD 1024
#define HH 16
#define DHH 64
#define NEGBIG (-3.0e38f)
// q pre-scale folds log2e so softmax uses native v_exp_f32 (2^x): exact transform.
#define QSCALE 0.1803368801111204f   // 0.125 * log2(e)
#define LN2F   0.6931471805599453f   // top = S' * ln2 recovers raw scores
#define DEFER_THR 12.0f              // defer-max threshold (log2 domain): P <= 2^12

__device__ inline u16 f2b(float f) {
  union { __hip_bfloat16 h; u16 u; } cv;
  cv.h = __float2bfloat16(f);  // RNE
  return cv.u;
}
__device__ inline float b2f(u16 u) {
  union { u16 u; __hip_bfloat16 h; } cv;
  cv.u = u;
  return __bfloat162float(cv.h);
}
__device__ inline float fin(float v, float sentinel) {
  return (fabsf(v) < 1e30f) ? v : sentinel;
}
__device__ inline float fexp2(float x) {
#if __has_builtin(__builtin_amdgcn_exp2f)
  return __builtin_amdgcn_exp2f(x);
#else
  return exp2f(x);
#endif
}
// async global->LDS, 16B/lane; LDS dst = wave-uniform base (+lane*16 implicit)
__device__ inline void async16(const void* g, void* l) {
  __builtin_amdgcn_global_load_lds(
      (__attribute__((address_space(1))) void*)(const_cast<void*>(g)),
      (__attribute__((address_space(3))) void*)l, 16, 0, 0);
}

// ===========================================================================
// FAST PATH
// ===========================================================================

// Prep: weight f32->bf16 conversions (jobs 0..3) + mask bit-pack (4) + amask (5).
// (R7-proven; R9's z-fold of mask-pack into the GEMM serialized instead of
// hiding -- rider blocks displace GEMM blocks on CUs. Reverted.)
__global__ __launch_bounds__(256) void convpack(
    const float* __restrict__ Wk, const float* __restrict__ Wv,
    const float* __restrict__ Wq, const float* __restrict__ Wo,
    const int* __restrict__ mask, const int* __restrict__ amask,
    u16* __restrict__ Wkb, u16* __restrict__ Wvb, u16* __restrict__ Wqb,
    u16* __restrict__ Wob, u32* __restrict__ maskb, u32* __restrict__ amaskb) {
  const int job = blockIdx.y;
  const int gtid = blockIdx.x * 256 + threadIdx.x;
  const int stride = gridDim.x * 256;

  if (job < 4) {
    const float* src; u16* dst;
    switch (job) {
      case 0: src = Wk; dst = Wkb; break;
      case 1: src = Wv; dst = Wvb; break;
      case 2: src = Wq; dst = Wqb; break;
      default: src = Wo; dst = Wob; break;
    }
    const size_t n4 = (size_t)DD * DD / 4;
    for (size_t i = gtid; i < n4; i += stride) {
      float4 v = ((const float4*)src)[i];
      short4v s;
      s[0] = (short)f2b(v.x); s[1] = (short)f2b(v.y);
      s[2] = (short)f2b(v.z); s[3] = (short)f2b(v.w);
      *(short4v*)(dst + i * 4) = s;
    }
  } else if (job == 4) {
    const size_t nw = (size_t)BB * LL * LL / 32;  // 262144 words
    for (size_t w = gtid; w < nw; w += stride) {
      const int4* src = (const int4*)(mask + w * 32);
      u32 bits = 0;
#pragma unroll
      for (int c = 0; c < 8; c++) {
        int4 v = src[c];
        bits |= (u32)(v.x != 0) << (c * 4);
        bits |= (u32)(v.y != 0) << (c * 4 + 1);
        bits |= (u32)(v.z != 0) << (c * 4 + 2);
        bits |= (u32)(v.w != 0) << (c * 4 + 3);
      }
      maskb[w] = bits;
    }
  } else {
    const int nw = BB * LL / 32;  // 256 words
    for (int w = gtid; w < nw; w += stride) {
      const int4* src = (const int4*)(amask + w * 32);
      u32 bits = 0;
#pragma unroll
      for (int c = 0; c < 8; c++) {
        int4 v = src[c];
        bits |= (u32)(v.x != 0) << (c * 4);
        bits |= (u32)(v.y != 0) << (c * 4 + 1);
        bits |= (u32)(v.z != 0) << (c * 4 + 2);
        bits |= (u32)(v.w != 0) << (c * 4 + 3);
      }
      amaskb[w] = bits;
    }
  }
}

// Merged QKV projection GEMM (R6/R7-proven deep-issue pipeline, unchanged).
// grid (64, 8, 3): z = 0:K 1:V 2:Q. f32 A direct, W bf16 via async16.
__global__ __launch_bounds__(256) void gemm_qkv(
    const float* __restrict__ key, const float* __restrict__ value,
    const float* __restrict__ query, const u16* __restrict__ Wkb,
    const u16* __restrict__ Wvb, const u16* __restrict__ Wqb,
    const float* __restrict__ bk, const float* __restrict__ bv,
    const float* __restrict__ bq, u16* __restrict__ kbuf,
    u16* __restrict__ vbt, u16* __restrict__ qbuf) {
  __shared__ u16 As[2][128 * 32];
  __shared__ u16 Ws[3][128 * 32];

  const int z = blockIdx.z;
  const int tid = threadIdx.x;
  const int wave = tid >> 6, lane = tid & 63;
  const int lr = lane & 15, lq = lane >> 4;
  const int row0 = blockIdx.x * 128;
  const int col0 = blockIdx.y * 128;
  const int wm = (wave & 1) * 64, wn = (wave >> 1) * 64;

  floatx4 acc[4][4];
#pragma unroll
  for (int i = 0; i < 4; i++)
#pragma unroll
    for (int j = 0; j < 4; j++) acc[i][j] = (floatx4){0.f, 0.f, 0.f, 0.f};

  const float* A = (z == 0) ? key : (z == 1) ? value : query;
  const u16* Wb  = (z == 0) ? Wkb : (z == 1) ? Wvb : Wqb;

  const int cc0 = tid, cc1 = 256 + tid;
  const u16* Wg0 = Wb + (size_t)(col0 + (cc0 >> 2)) * 1024 + (cc0 & 3) * 8;
  const u16* Wg1 = Wb + (size_t)(col0 + (cc1 >> 2)) * 1024 + (cc1 & 3) * 8;

  auto stageW = [&](int t, int wbuf) {
    const int o = t * 32;
    async16(Wg0 + o, &Ws[wbuf][wave * 512]);
    async16(Wg1 + o, &Ws[wbuf][2048 + wave * 512]);
  };
  auto loadA = [&](int t, float4* ag) {
#pragma unroll
    for (int it = 0; it < 4; it++) {
      const int cc = it * 256 + tid;
      ag[it] = *(const float4*)(A + (size_t)(row0 + (cc >> 3)) * 1024 +
                                (cc & 7) * 4 + t * 32);
    }
  };
  auto writeA = [&](int abuf, const float4* ag) {
#pragma unroll
    for (int it = 0; it < 4; it++) {
      const int cc = it * 256 + tid;
      short4v s;
      s[0] = (short)f2b(ag[it].x); s[1] = (short)f2b(ag[it].y);
      s[2] = (short)f2b(ag[it].z); s[3] = (short)f2b(ag[it].w);
      *(short4v*)(&As[abuf][(cc >> 3) * 32 + (cc & 7) * 4]) = s;
    }
  };

  float4 ag[3][4];

  // Prologue. Ledger after each line in comments (oldest -> newest).
  stageW(0, 0);                                        // [W0:2]
  stageW(1, 1);                                        // [W0,W1] = 4
  loadA(0, ag[0]);                                     // [W0,W1,A0] = 8
  loadA(1, ag[1]);                                     // [..,A1] = 12
  asm volatile("s_waitcnt vmcnt(4)" ::: "memory");     // retire W0,W1,A0 -> [A1]
  writeA(0, ag[0]);
  loadA(2, ag[2]);                                     // [A1,A2] = 8

#pragma unroll
  for (int t = 0; t < 32; t++) {
    const int abuf = t & 1;
    // T1: retire W(t) (per-wave, BEFORE barrier -> cross-wave LDS visibility)
    asm volatile("s_waitcnt vmcnt(10)" ::: "memory");
    // T2: my ds_writes of As[abuf] (from t-1) complete before barrier
    asm volatile("s_waitcnt lgkmcnt(0)" ::: "memory");
    __builtin_amdgcn_s_barrier();
    asm volatile("" ::: "memory");  // no memory-op hoisting above the barrier

    const int t2 = (t + 2 < 32) ? t + 2 : 31;
    const int t3 = (t + 3 < 32) ? t + 3 : 31;
    stageW(t2, (t + 2) % 3);        // +2
    loadA(t3, ag[t % 3]);           // +4

    short8 af[4], wf[4];
#pragma unroll
    for (int mi = 0; mi < 4; mi++)
      af[mi] = *(const short8*)(&As[abuf][(wm + mi * 16 + lr) * 32 + lq * 8]);
#pragma unroll
    for (int ni = 0; ni < 4; ni++)
      wf[ni] = *(const short8*)(&Ws[t % 3][(wn + ni * 16 + lr) * 32 + lq * 8]);
#pragma unroll
    for (int mi = 0; mi < 4; mi++)
#pragma unroll
      for (int ni = 0; ni < 4; ni++)
        acc[mi][ni] = __builtin_amdgcn_mfma_f32_16x16x32_bf16(af[mi], wf[ni],
                                                              acc[mi][ni], 0, 0, 0);

    // T7: retire A(t+1) (private regs; matches compiler's own auto-wait)
    if (t == 0) asm volatile("s_waitcnt vmcnt(10)" ::: "memory");
    else        asm volatile("s_waitcnt vmcnt(12)" ::: "memory");
    writeA(abuf ^ 1, ag[(t + 1) % 3]);
  }

  const float scale = (z == 2) ? QSCALE : 1.0f;
  const float* bias = (z == 0) ? bk : (z == 1) ? bv : bq;
  u16* outb = (z == 0) ? kbuf : qbuf;

#pragma unroll
  for (int ni = 0; ni < 4; ni++) {
    const int col = col0 + wn + ni * 16 + lr;
    const float bvv = bias[col];
#pragma unroll
    for (int mi = 0; mi < 4; mi++) {
#pragma unroll
      for (int r = 0; r < 4; r++) {
        const int row = row0 + wm + mi * 16 + lq * 4 + r;
        const float v = (acc[mi][ni][r] + bvv) * scale;
        const int b = row >> 10, l = row & 1023, h = col >> 6, dh = col & 63;
        if (z == 1)
          vbt[((b * HH + h) * DHH + dh) * LL + l] = f2b(v);   // (B,H,DH,L)
        else
          outb[((b * HH + h) * LL + l) * DHH + dh] = f2b(v);  // (B,H,L,DH)
      }
    }
  }
}

// bf16 GEMM (O-projection), R6 deep-issue (unchanged, proven).
template <int OUT>
__global__ __launch_bounds__(256) void gemm_b(
    const u16* __restrict__ A, const u16* __restrict__ Wb,
    const float* __restrict__ bias, void* __restrict__ outv, float scale) {
  __shared__ u16 As[3][128 * 32];
  __shared__ u16 Ws[3][128 * 32];

  const int tid = threadIdx.x;
  const int wave = tid >> 6, lane = tid & 63;
  const int lr = lane & 15, lq = lane >> 4;
  const int row0 = blockIdx.x * 128;
  const int col0 = blockIdx.y * 128;
  const int wm = (wave & 1) * 64, wn = (wave >> 1) * 64;

  floatx4 acc[4][4];
#pragma unroll
  for (int i = 0; i < 4; i++)
#pragma unroll
    for (int j = 0; j < 4; j++) acc[i][j] = (floatx4){0.f, 0.f, 0.f, 0.f};

  const int cc0 = tid, cc1 = 256 + tid;
  const u16* Ag0 = A + (size_t)(row0 + (cc0 >> 2)) * 1024 + (cc0 & 3) * 8;
  const u16* Ag1 = A + (size_t)(row0 + (cc1 >> 2)) * 1024 + (cc1 & 3) * 8;
  const u16* Wg0 = Wb + (size_t)(col0 + (cc0 >> 2)) * 1024 + (cc0 & 3) * 8;
  const u16* Wg1 = Wb + (size_t)(col0 + (cc1 >> 2)) * 1024 + (cc1 & 3) * 8;

  auto stage = [&](int t, int buf) {
    const int o = t * 32;
    async16(Ag0 + o, &As[buf][wave * 512]);
    async16(Ag1 + o, &As[buf][2048 + wave * 512]);
    async16(Wg0 + o, &Ws[buf][wave * 512]);
    async16(Wg1 + o, &Ws[buf][2048 + wave * 512]);
  };

  stage(0, 0);   // [S0:4]
  stage(1, 1);   // [S0,S1] = 8

#pragma unroll
  for (int t = 0; t < 32; t++) {
    // retire S(t) per-wave BEFORE the barrier -> tile t LDS-resident for all
    asm volatile("s_waitcnt vmcnt(4)" ::: "memory");
    __builtin_amdgcn_s_barrier();
    asm volatile("" ::: "memory");

    const int t2 = (t + 2 < 32) ? t + 2 : 31;
    stage(t2, (t + 2) % 3);

    short8 af[4], wf[4];
#pragma unroll
    for (int mi = 0; mi < 4; mi++)
      af[mi] = *(const short8*)(&As[t % 3][(wm + mi * 16 + lr) * 32 + lq * 8]);
#pragma unroll
    for (int ni = 0; ni < 4; ni++)
      wf[ni] = *(const short8*)(&Ws[t % 3][(wn + ni * 16 + lr) * 32 + lq * 8]);
#pragma unroll
    for (int mi = 0; mi < 4; mi++)
#pragma unroll
      for (int ni = 0; ni < 4; ni++)
        acc[mi][ni] = __builtin_amdgcn_mfma_f32_16x16x32_bf16(af[mi], wf[ni],
                                                              acc[mi][ni], 0, 0, 0);
  }

#pragma unroll
  for (int ni = 0; ni < 4; ni++) {
    const int col = col0 + wn + ni * 16 + lr;
    const float bv = bias[col];
#pragma unroll
    for (int mi = 0; mi < 4; mi++) {
#pragma unroll
      for (int r = 0; r < 4; r++) {
        const int row = row0 + wm + mi * 16 + lq * 4 + r;
        const float v = (acc[mi][ni][r] + bv) * scale;
        if (OUT == 0) {
          const int b = row >> 10, l = row & 1023, h = col >> 6, dh = col & 63;
          ((u16*)outv)[((b * HH + h) * LL + l) * DHH + dh] = f2b(v);
        } else if (OUT == 2) {
          const int b = row >> 10, l = row & 1023, h = col >> 6, dh = col & 63;
          ((u16*)outv)[((b * HH + h) * DHH + dh) * LL + l] = f2b(v);
        } else {
          ((float*)outv)[(size_t)row * 1024 + col] = v;
        }
      }
    }
  }
}

// Flash attention (R7-proven body) + folded top blocks (id >= 1024, R9-proven
// correct): top blocks are strictly shorter than attn blocks -> no straggler
// tail; saves one launch + inter-launch gap.
__global__ __launch_bounds__(256) void attn_fast(
    const u16* __restrict__ qbuf, const u16* __restrict__ kbuf,
    const u16* __restrict__ vbt, const u32* __restrict__ maskb,
    const u32* __restrict__ amaskb, u16* __restrict__ ctx,
    float* __restrict__ top) {
  __shared__ u16 Ks[2][64 * 64];
  __shared__ u16 Vts[2][64 * 64];   // [dh][key], granule-swizzled

  const int id = blockIdx.x;
  const int tid = threadIdx.x, wave = tid >> 6, lane = tid & 63;
  const int lr = lane & 15, lq = lane >> 4;
  const int lq4 = lq * 4;
  const int x7 = lr & 7;
  const int cs0 = ((0 + lq) ^ x7) * 8;
  const int cs1 = ((4 + lq) ^ x7) * 8;

  if (id >= 1024) {
    // ---- top path: top[b] = (K0 . Q0^T) * ln2 (R7 top_kernel body) ----
    const int id2 = id - 1024;
    const int kt = id2 & 7, qt = (id2 >> 3) & 7, b = id2 >> 6;
    u16* Qs = &Ks[0][0];    // 16 KB
    u16* Kts = &Vts[0][0];  // 16 KB

    const u16* Qg = qbuf + (size_t)((b * HH + 0) * LL + qt * 128) * DHH;
    const u16* Kg = kbuf + (size_t)((b * HH + 0) * LL + kt * 128) * DHH;

#pragma unroll
    for (int rnd = 0; rnd < 4; rnd++) {
      const int g = rnd * 256 + tid;
      const int row = g >> 3, col = (g & 7) ^ (row & 7);
      async16(Qg + row * 64 + col * 8, Qs + (rnd * 256 + wave * 64) * 8);
      async16(Kg + row * 64 + col * 8, Kts + (rnd * 256 + wave * 64) * 8);
    }
    __syncthreads();

    short8 qf[2][2];
#pragma unroll
    for (int mi = 0; mi < 2; mi++) {
      qf[mi][0] = *(const short8*)(Qs + (wave * 32 + mi * 16 + lr) * 64 + cs0);
      qf[mi][1] = *(const short8*)(Qs + (wave * 32 + mi * 16 + lr) * 64 + cs1);
    }

#pragma unroll
    for (int nj = 0; nj < 8; nj++) {
      const short8 kf0 = *(const short8*)(Kts + (nj * 16 + lr) * 64 + cs0);
      const short8 kf1 = *(const short8*)(Kts + (nj * 16 + lr) * 64 + cs1);
#pragma unroll
      for (int mi = 0; mi < 2; mi++) {
        floatx4 z = (floatx4){0.f, 0.f, 0.f, 0.f};
        z = __builtin_amdgcn_mfma_f32_16x16x32_bf16(kf1, qf[mi][1], z, 0, 0, 0);
        z = __builtin_amdgcn_mfma_f32_16x16x32_bf16(kf0, qf[mi][0], z, 0, 0, 0);
        const int row = qt * 128 + wave * 32 + mi * 16 + lr;
        float4 t;
        t.x = z[0] * LN2F; t.y = z[1] * LN2F;
        t.z = z[2] * LN2F; t.w = z[3] * LN2F;
        *(float4*)(top + (size_t)(b * LL + row) * LL + kt * 128 + nj * 16 + lq4) = t;
      }
    }
    return;
  }

  // ---- attention path (R7-proven, unchanged) ----
  const int xcd = id & 7;
  const int r_ = id >> 3;
  const int b = r_ & 7;
  const int h = (((r_ >> 3) & 1) << 3) | (xcd ^ b);
  const int qt = r_ >> 4;

  const u16* Qg = qbuf + (size_t)((b * HH + h) * LL + qt * 128) * DHH;
  const u16* Kg = kbuf + (size_t)((b * HH + h) * LL) * DHH;
  const u16* Vtg = vbt + (size_t)((b * HH + h) * DHH) * LL;  // [dh][l]

  short8 qf[2][2];
#pragma unroll
  for (int mi = 0; mi < 2; mi++)
#pragma unroll
    for (int kk = 0; kk < 2; kk++)
      qf[mi][kk] = *(const short8*)(Qg + (wave * 32 + mi * 16 + lr) * 64 +
                                    kk * 32 + lq * 8);

  const int g0 = tid, g1 = 256 + tid;
  const int kr0 = g0 >> 3, kc0 = (g0 & 7) ^ (kr0 & 7);
  const int kr1 = g1 >> 3, kc1 = (g1 & 7) ^ (kr1 & 7);
  const int lqh = lq >> 1, lqb = (lq & 1) * 4;
  const int go00 = ((0 + lqh) ^ x7) * 8 + lqb;  // kk=0 lo
  const int go01 = ((2 + lqh) ^ x7) * 8 + lqb;  // kk=0 hi
  const int go10 = ((4 + lqh) ^ x7) * 8 + lqb;  // kk=1 lo
  const int go11 = ((6 + lqh) ^ x7) * 8 + lqb;  // kk=1 hi

  auto stage = [&](int kc, int buf) {
    async16(Kg + kc * 4096 + kr0 * 64 + kc0 * 8, &Ks[buf][wave * 512]);
    async16(Kg + kc * 4096 + kr1 * 64 + kc1 * 8, &Ks[buf][2048 + wave * 512]);
    async16(Vtg + (size_t)kr0 * LL + kc * 64 + kc0 * 8, &Vts[buf][wave * 512]);
    async16(Vtg + (size_t)kr1 * LL + kc * 64 + kc1 * 8,
            &Vts[buf][2048 + wave * 512]);
  };

  const int rowm0 = qt * 128 + wave * 32 + lr;         // mi=0 row
  const int rowm1 = rowm0 + 16;                        // mi=1 row
  const u32* mb0 = (h < 8) ? maskb + (size_t)(b * LL + rowm0) * 32
                           : amaskb + b * 32;
  const u32* mb1 = (h < 8) ? maskb + (size_t)(b * LL + rowm1) * 32
                           : amaskb + b * 32;
  uint2 mwc0 = *(const uint2*)(mb0);
  uint2 mwc1 = *(const uint2*)(mb1);

  float mrow[2], lrow[2];
  floatx4 Oacc[2][4];
#pragma unroll
  for (int mi = 0; mi < 2; mi++) {
    mrow[mi] = NEGBIG;
    lrow[mi] = 0.f;
#pragma unroll
    for (int ni = 0; ni < 4; ni++) Oacc[mi][ni] = (floatx4){0.f, 0.f, 0.f, 0.f};
  }

  stage(0, 0);

  for (int kc = 0; kc < 16; kc++) {
    const int cur = kc & 1;
    __syncthreads();
    uint2 mwn0, mwn1;
    if (kc < 15) {
      stage(kc + 1, cur ^ 1);
      mwn0 = *(const uint2*)(mb0 + (kc + 1) * 2);   // in flight during compute
      mwn1 = *(const uint2*)(mb1 + (kc + 1) * 2);
    }
    const u16* Ksc = Ks[cur];
    const u16* Vtsc = Vts[cur];

    floatx4 S[2][4];
    __builtin_amdgcn_s_setprio(1);
#pragma unroll
    for (int nj = 0; nj < 4; nj++) {
      const short8 kf0 = *(const short8*)(Ksc + (nj * 16 + lr) * 64 + cs0);
      const short8 kf1 = *(const short8*)(Ksc + (nj * 16 + lr) * 64 + cs1);
#pragma unroll
      for (int mi = 0; mi < 2; mi++) {
        floatx4 z = (floatx4){0.f, 0.f, 0.f, 0.f};
        z = __builtin_amdgcn_mfma_f32_16x16x32_bf16(kf1, qf[mi][1], z, 0, 0, 0);
        z = __builtin_amdgcn_mfma_f32_16x16x32_bf16(kf0, qf[mi][0], z, 0, 0, 0);
        S[mi][nj] = z;
      }
    }
    __builtin_amdgcn_s_setprio(0);

    short8 pf[2][2];
#pragma unroll
    for (int mi = 0; mi < 2; mi++) {
      {
        const uint2 mw = mi ? mwc1 : mwc0;
#pragma unroll
        for (int nj = 0; nj < 4; nj++) {
          const u32 nib = (((nj & 2) ? mw.y : mw.x) >> ((nj & 1) * 16 + lq4)) & 15u;
#pragma unroll
          for (int r = 0; r < 4; r++)
            if ((nib >> r) & 1) S[mi][nj][r] = -1e18f;
        }
      }

      // online softmax (exp2 domain) with defer-max (T13)
      float cm = fmaxf(fmaxf(S[mi][0][0], S[mi][0][1]),
                       fmaxf(S[mi][0][2], S[mi][0][3]));
#pragma unroll
      for (int nj = 1; nj < 4; nj++)
        cm = fmaxf(cm, fmaxf(fmaxf(S[mi][nj][0], S[mi][nj][1]),
                             fmaxf(S[mi][nj][2], S[mi][nj][3])));
      cm = fmaxf(cm, __shfl_xor(cm, 16, 64));
      cm = fmaxf(cm, __shfl_xor(cm, 32, 64));
      const float mold = mrow[mi];
      if (!__all(cm <= mold + DEFER_THR)) {
        const float mnew = fmaxf(mold, cm);
        const float alpha = fexp2(mold - mnew);
        mrow[mi] = mnew;
        lrow[mi] *= alpha;
#pragma unroll
        for (int ni = 0; ni < 4; ni++)
#pragma unroll
          for (int r = 0; r < 4; r++) Oacc[mi][ni][r] *= alpha;
      }
      const float mcur = mrow[mi];
      float rs = 0.f;
#pragma unroll
      for (int nj = 0; nj < 4; nj++)
#pragma unroll
        for (int r = 0; r < 4; r++) {
          const float p = fexp2(S[mi][nj][r] - mcur);
          S[mi][nj][r] = p;
          rs += p;
        }
      rs += __shfl_xor(rs, 16, 64);
      rs += __shfl_xor(rs, 32, 64);
      lrow[mi] += rs;

      // P fragment under key-relabeling kappa (R2-proven)
#pragma unroll
      for (int kk = 0; kk < 2; kk++) {
        short8 p;
#pragma unroll
        for (int r = 0; r < 4; r++) {
          p[r] = (short)f2b(S[mi][2 * kk][r]);
          p[4 + r] = (short)f2b(S[mi][2 * kk + 1][r]);
        }
        pf[mi][kk] = p;
      }
    }

    __builtin_amdgcn_s_setprio(1);
#pragma unroll
    for (int ni = 0; ni < 4; ni++) {
      const int rb = (ni * 16 + lr) * 64;
      const short4v v00 = *(const short4v*)(Vtsc + rb + go00);
      const short4v v01 = *(const short4v*)(Vtsc + rb + go01);
      const short4v v10 = *(const short4v*)(Vtsc + rb + go10);
      const short4v v11 = *(const short4v*)(Vtsc + rb + go11);
      const short8 vf0 = __builtin_shufflevector(v00, v01, 0, 1, 2, 3, 4, 5, 6, 7);
      const short8 vf1 = __builtin_shufflevector(v10, v11, 0, 1, 2, 3, 4, 5, 6, 7);
#pragma unroll
      for (int mi = 0; mi < 2; mi++) {
        Oacc[mi][ni] =
            __builtin_amdgcn_mfma_f32_16x16x32_bf16(vf0, pf[mi][0], Oacc[mi][ni], 0, 0, 0);
        Oacc[mi][ni] =
            __builtin_amdgcn_mfma_f32_16x16x32_bf16(vf1, pf[mi][1], Oacc[mi][ni], 0, 0, 0);
      }
    }
    __builtin_amdgcn_s_setprio(0);

    if (kc < 15) { mwc0 = mwn0; mwc1 = mwn1; }
  }

#pragma unroll
  for (int mi = 0; mi < 2; mi++) {
    const float inv = 1.0f / lrow[mi];
    const int row = qt * 128 + wave * 32 + mi * 16 + lr;
    u16* cp = ctx + (size_t)(b * LL + row) * DD + h * DHH + lq4;
#pragma unroll
    for (int ni = 0; ni < 4; ni++) {
      short4v o;
      o[0] = (short)f2b(Oacc[mi][ni][0] * inv);
      o[1] = (short)f2b(Oacc[mi][ni][1] * inv);
      o[2] = (short)f2b(Oacc[mi][ni][2] * inv);
      o[3] = (short)f2b(Oacc[mi][ni][3] * inv);
      *(short4v*)(cp + ni * 16) = o;
    }
  }
}

// ===========================================================================
// FALLBACK PATH (R5-proven, 64 MB ws)
// ===========================================================================
template <int MODE>
__global__ __launch_bounds__(256) void gemm_k(
    const void* __restrict__ Av, const float* __restrict__ W,
    const float* __restrict__ biasp, void* __restrict__ outv, float scale) {
  __shared__ u16 As[128 * 32];
  __shared__ u16 Ws[128 * 32];
  const int tid = threadIdx.x;
  const int wave = tid >> 6, lane = tid & 63;
  const int lr = lane & 15, lq = lane >> 4;
  const int row0 = blockIdx.x * 128;
  const int col0 = blockIdx.y * 128;
  const int wm = (wave & 1) * 64, wn = (wave >> 1) * 64;
  floatx4 acc[4][4];
#pragma unroll
  for (int i = 0; i < 4; i++)
#pragma unroll
    for (int j = 0; j < 4; j++) acc[i][j] = (floatx4){0.f, 0.f, 0.f, 0.f};
  const float* Af = (const float*)Av;
  const u16* Ab = (const u16*)Av;
  for (int k0 = 0; k0 < 1024; k0 += 32) {
    float4 wg[4];
#pragma unroll
    for (int it = 0; it < 4; it++) {
      const int cc = it * 256 + tid;
      wg[it] = *(const float4*)(W + (size_t)(col0 + (cc >> 3)) * 1024 + (cc & 7) * 4 + k0);
    }
    float4 ag[4];
    short8 ab0, ab1;
    if (MODE == 0) {
#pragma unroll
      for (int it = 0; it < 4; it++) {
        const int cc = it * 256 + tid;
        ag[it] = *(const float4*)(Af + (size_t)(row0 + (cc >> 3)) * 1024 + (cc & 7) * 4 + k0);
      }
    } else {
      const int cc0 = tid, cc1 = 256 + tid;
      ab0 = *(const short8*)(Ab + (size_t)(row0 + (cc0 >> 2)) * 1024 + (cc0 & 3) * 8 + k0);
      ab1 = *(const short8*)(Ab + (size_t)(row0 + (cc1 >> 2)) * 1024 + (cc1 & 3) * 8 + k0);
    }
    __syncthreads();
#pragma unroll
    for (int it = 0; it < 4; it++) {
      const int cc = it * 256 + tid;
      short4v s;
      s[0] = (short)f2b(wg[it].x); s[1] = (short)f2b(wg[it].y);
      s[2] = (short)f2b(wg[it].z); s[3] = (short)f2b(wg[it].w);
      *(short4v*)(Ws + (cc >> 3) * 32 + (cc & 7) * 4) = s;
    }
    if (MODE == 0) {
#pragma unroll
      for (int it = 0; it < 4; it++) {
        const int cc = it * 256 + tid;
        short4v s;
        s[0] = (short)f2b(ag[it].x); s[1] = (short)f2b(ag[it].y);
        s[2] = (short)f2b(ag[it].z); s[3] = (short)f2b(ag[it].w);
        *(short4v*)(As + (cc >> 3) * 32 + (cc & 7) * 4) = s;
      }
    } else {
      *(short8*)(As + tid * 8) = ab0;
      *(short8*)(As + (256 + tid) * 8) = ab1;
    }
    __syncthreads();
    short8 af[4], wf[4];
#pragma unroll
    for (int mi = 0; mi < 4; mi++)
      af[mi] = *(const short8*)(As + (wm + mi * 16 + lr) * 32 + lq * 8);
#pragma unroll
    for (int ni = 0; ni < 4; ni++)
      wf[ni] = *(const short8*)(Ws + (wn + ni * 16 + lr) * 32 + lq * 8);
#pragma unroll
    for (int mi = 0; mi < 4; mi++)
#pragma unroll
      for (int ni = 0; ni < 4; ni++)
        acc[mi][ni] = __builtin_amdgcn_mfma_f32_16x16x32_bf16(af[mi], wf[ni], acc[mi][ni], 0, 0, 0);
  }
#pragma unroll
  for (int ni = 0; ni < 4; ni++) {
    const int col = col0 + wn + ni * 16 + lr;
    const float bv = biasp[col];
#pragma unroll
    for (int mi = 0; mi < 4; mi++) {
#pragma unroll
      for (int r = 0; r < 4; r++) {
        const int row = row0 + wm + mi * 16 + lq * 4 + r;
        float v = (acc[mi][ni][r] + bv) * scale;
        v = fin(v, MODE == 0 ? 700.0f : 1000.0f);
        if (MODE == 0) {
          const int b = row >> 10, l = row & 1023, h = col >> 6, dh = col & 63;
          ((u16*)outv)[((b * HH + h) * LL + l) * DHH + dh] = f2b(v);
        } else {
          ((float*)outv)[(size_t)row * 1024 + col] = v;
        }
      }
    }
  }
}

__global__ __launch_bounds__(256) void attn_kernel(
    const u16* __restrict__ qbuf, const u16* __restrict__ kbuf,
    const u16* __restrict__ vbuf, const int* __restrict__ mask,
    const int* __restrict__ amask, u16* __restrict__ ctx,
    float* __restrict__ top) {
  __shared__ u16 Qs[128 * 64];
  __shared__ u16 Ks[64 * 64];
  __shared__ u16 Vts[64 * 64];
  __shared__ u16 Ps[4][32 * 64];
  const int qt = blockIdx.x, h = blockIdx.y, b = blockIdx.z;
  const int tid = threadIdx.x, wave = tid >> 6, lane = tid & 63;
  const int lr = lane & 15, lq = lane >> 4;
  const u16* Qg = qbuf + (size_t)((b * HH + h) * LL + qt * 128) * DHH;
  const u16* Kg = kbuf + (size_t)((b * HH + h) * LL) * DHH;
  const u16* Vg = vbuf + (size_t)((b * HH + h) * LL) * DHH;
#pragma unroll
  for (int it = 0; it < 4; it++) {
    short8 qv = *(const short8*)(Qg + (it * 256 + tid) * 8);
    *(short8*)(Qs + (it * 256 + tid) * 8) = qv;
  }
  float mrow[2][4], lrow[2][4];
  floatx4 Oacc[2][4];
#pragma unroll
  for (int mi = 0; mi < 2; mi++)
#pragma unroll
    for (int r = 0; r < 4; r++) { mrow[mi][r] = NEGBIG; lrow[mi][r] = 0.f; }
#pragma unroll
  for (int mi = 0; mi < 2; mi++)
#pragma unroll
    for (int ni = 0; ni < 4; ni++) Oacc[mi][ni] = (floatx4){0.f, 0.f, 0.f, 0.f};
  for (int kc = 0; kc < 16; kc++) {
    const u16* Kc = Kg + kc * 64 * DHH;
    const u16* Vc = Vg + kc * 64 * DHH;
    short8 kv0 = *(const short8*)(Kc + tid * 8);
    short8 kv1 = *(const short8*)(Kc + (256 + tid) * 8);
    short8 vv0 = *(const short8*)(Vc + tid * 8);
    short8 vv1 = *(const short8*)(Vc + (256 + tid) * 8);
    __syncthreads();
    *(short8*)(Ks + tid * 8) = kv0;
    *(short8*)(Ks + (256 + tid) * 8) = kv1;
    {
      const int r0 = tid >> 3, e0 = (tid & 7) * 8;
#pragma unroll
      for (int j = 0; j < 8; j++) Vts[(e0 + j) * 64 + r0] = (u16)vv0[j];
      const int cc1 = 256 + tid;
      const int r1 = cc1 >> 3, e1 = (cc1 & 7) * 8;
#pragma unroll
      for (int j = 0; j < 8; j++) Vts[(e1 + j) * 64 + r1] = (u16)vv1[j];
    }
    __syncthreads();
    floatx4 S[2][4];
    short8 qf[2][2];
#pragma unroll
    for (int mi = 0; mi < 2; mi++)
#pragma unroll
      for (int kk = 0; kk < 2; kk++)
        qf[mi][kk] = *(const short8*)(Qs + (wave * 32 + mi * 16 + lr) * 64 + kk * 32 + lq * 8);
#pragma unroll
    for (int nj = 0; nj < 4; nj++) {
      short8 kf0 = *(const short8*)(Ks + (nj * 16 + lr) * 64 + lq * 8);
      short8 kf1 = *(const short8*)(Ks + (nj * 16 + lr) * 64 + 32 + lq * 8);
#pragma unroll
      for (int mi = 0; mi < 2; mi++) {
        floatx4 z = (floatx4){0.f, 0.f, 0.f, 0.f};
        z = __builtin_amdgcn_mfma_f32_16x16x32_bf16(qf[mi][1], kf1, z, 0, 0, 0);
        z = __builtin_amdgcn_mfma_f32_16x16x32_bf16(qf[mi][0], kf0, z, 0, 0, 0);
        S[mi][nj] = z;
      }
    }
#pragma unroll
    for (int mi = 0; mi < 2; mi++)
#pragma unroll
      for (int nj = 0; nj < 4; nj++)
#pragma unroll
        for (int r = 0; r < 4; r++) S[mi][nj][r] = fin(S[mi][nj][r], 800.0f);
    if (h == 0) {
#pragma unroll
      for (int mi = 0; mi < 2; mi++)
#pragma unroll
        for (int nj = 0; nj < 4; nj++)
#pragma unroll
          for (int r = 0; r < 4; r++) {
            const int row = qt * 128 + wave * 32 + mi * 16 + lq * 4 + r;
            const int colk = kc * 64 + nj * 16 + lr;
            top[(size_t)(b * LL + row) * LL + colk] = S[mi][nj][r];
          }
    }
    if (h < 8) {
#pragma unroll
      for (int mi = 0; mi < 2; mi++)
#pragma unroll
        for (int r = 0; r < 4; r++) {
          const int row = qt * 128 + wave * 32 + mi * 16 + lq * 4 + r;
          const int* mp = mask + (size_t)(b * LL + row) * LL + kc * 64;
#pragma unroll
          for (int nj = 0; nj < 4; nj++) {
            const int mv = mp[nj * 16 + lr];
            S[mi][nj][r] = mv ? -1e18f : S[mi][nj][r];
          }
        }
    } else {
#pragma unroll
      for (int nj = 0; nj < 4; nj++) {
        const int mv = amask[b * LL + kc * 64 + nj * 16 + lr];
        if (mv) {
#pragma unroll
          for (int mi = 0; mi < 2; mi++)
#pragma unroll
            for (int r = 0; r < 4; r++) S[mi][nj][r] = -1e18f;
        }
      }
    }
#pragma unroll
    for (int mi = 0; mi < 2; mi++) {
#pragma unroll
      for (int r = 0; r < 4; r++) {
        float cm = S[mi][0][r];
#pragma unroll
        for (int nj = 1; nj < 4; nj++) cm = fmaxf(cm, S[mi][nj][r]);
#pragma unroll
        for (int off = 1; off < 16; off <<= 1) cm = fmaxf(cm, __shfl_xor(cm, off, 64));
        const float mold = mrow[mi][r];
        const float mnew = fmaxf(mold, cm);
        const float alpha = __expf(mold - mnew);
        mrow[mi][r] = mnew;
        float rs = 0.f;
#pragma unroll
        for (int nj = 0; nj < 4; nj++) {
          const float p = __expf(S[mi][nj][r] - mnew);
          S[mi][nj][r] = p;
          rs += p;
        }
#pragma unroll
        for (int off = 1; off < 16; off <<= 1) rs += __shfl_xor(rs, off, 64);
        lrow[mi][r] = lrow[mi][r] * alpha + rs;
#pragma unroll
        for (int ni = 0; ni < 4; ni++) Oacc[mi][ni][r] *= alpha;
      }
    }
#pragma unroll
    for (int mi = 0; mi < 2; mi++)
#pragma unroll
      for (int nj = 0; nj < 4; nj++)
#pragma unroll
        for (int r = 0; r < 4; r++)
          Ps[wave][(mi * 16 + lq * 4 + r) * 64 + nj * 16 + lr] = f2b(S[mi][nj][r]);
    __syncthreads();
#pragma unroll
    for (int kk = 0; kk < 2; kk++) {
      short8 pf[2];
#pragma unroll
      for (int mi = 0; mi < 2; mi++)
        pf[mi] = *(const short8*)(&Ps[wave][(mi * 16 + lr) * 64 + kk * 32 + lq * 8]);
#pragma unroll
      for (int ni = 0; ni < 4; ni++) {
        short8 vf = *(const short8*)(Vts + (ni * 16 + lr) * 64 + kk * 32 + lq * 8);
#pragma unroll
        for (int mi = 0; mi < 2; mi++)
          Oacc[mi][ni] = __builtin_amdgcn_mfma_f32_16x16x32_bf16(pf[mi], vf, Oacc[mi][ni], 0, 0, 0);
      }
    }
  }
#pragma unroll
  for (int mi = 0; mi < 2; mi++)
#pragma unroll
    for (int r = 0; r < 4; r++) {
      const float inv = 1.0f / lrow[mi][r];
      const int row = qt * 128 + wave * 32 + mi * 16 + lq * 4 + r;
#pragma unroll
      for (int ni = 0; ni < 4; ni++) {
        const int col = h * DHH + ni * 16 + lr;
        ctx[(size_t)(b * LL + row) * DD + col] = f2b(fin(Oacc[mi][ni][r] * inv, 900.0f));
      }
    }
}

// ===========================================================================
extern "C" void kernel_launch(void* const* d_in, const int* in_sizes, int n_in,
                              void* d_out, int out_size, void* d_ws, size_t ws_size,
                              hipStream_t stream) {
  const float* key   = (const float*)d_in[0];
  const float* value = (const float*)d_in[1];
  const float* query = (const float*)d_in[2];
  const int* mask    = (const int*)d_in[3];
  const int* amask   = (const int*)d_in[4];
  const float* Wk = (const float*)d_in[5];
  const float* bk = (const float*)d_in[6];
  const float* Wv = (const float*)d_in[7];
  const float* bv = (const float*)d_in[8];
  const float* Wq = (const float*)d_in[9];
  const float* bq = (const float*)d_in[10];
  const float* Wo = (const float*)d_in[11];
  const float* bo = (const float*)d_in[12];

  float* outp = (float*)d_out;                  // out (B,L,D) f32
  float* topp = outp + (size_t)BB * LL * DD;    // top_score (B,L,L) f32

  const size_t M8 = (size_t)BB * LL * DD;       // 8M elems
  const size_t M1 = (size_t)DD * DD;            // 1M elems
  const size_t NEED = (size_t)90 * 1024 * 1024; // fast-path ws bytes

  dim3 tb(256), gg(64, 8, 1), ga(8, 16, 8);

  if (ws_size >= NEED) {
    u16* W16 = (u16*)d_ws;
    u16* Wkb = W16;                              // 4 weight buffers (bf16)
    u16* Wvb = Wkb + M1;
    u16* Wqb = Wvb + M1;
    u16* Wob = Wqb + M1;
    u32* maskb = (u32*)(Wob + M1);               // 1 MB (+1 KB) in slots 4-5
    u32* amaskb = maskb + 262144;
    u16* kbuf = W16 + 6 * M1;                    // 16 MB each
    u16* vbt  = kbuf + M8;
    u16* qbuf = vbt + M8;
    u16* cbuf = qbuf + M8;

    convpack<<<dim3(256, 6), tb, 0, stream>>>(
        Wk, Wv, Wq, Wo, mask, amask, Wkb, Wvb, Wqb, Wob, maskb, amaskb);
    gemm_qkv<<<dim3(64, 8, 3), tb, 0, stream>>>(
        key, value, query, Wkb, Wvb, Wqb, bk, bv, bq, kbuf, vbt, qbuf);
    attn_fast<<<dim3(1536, 1, 1), tb, 0, stream>>>(qbuf, kbuf, vbt, maskb,
                                                   amaskb, cbuf, topp);
    gemm_b<1><<<gg, tb, 0, stream>>>(cbuf, Wob, bo, outp, 1.0f);
  } else {
    u16* kbuf = (u16*)d_ws;
    u16* vbuf = kbuf + M8;
    u16* qbuf = vbuf + M8;
    u16* cbuf = qbuf + M8;
    gemm_k<0><<<gg, tb, 0, stream>>>(key,   Wk, bk, kbuf, 1.0f);
    gemm_k<0><<<gg, tb, 0, stream>>>(value, Wv, bv, vbuf, 1.0f);
    gemm_k<0><<<gg, tb, 0, stream>>>(query, Wq, bq, qbuf, 0.125f);
    attn_kernel<<<ga, tb, 0, stream>>>(qbuf, kbuf, vbuf, mask, amask, cbuf, topp);
    gemm_k<1><<<gg, tb, 0, stream>>>(cbuf, Wo, bo, outp, 1.0f);
  }
}